// Round 15
// baseline (357.609 us; speedup 1.0000x reference)
//
#include <hip/hip_runtime.h>
#include <math.h>

#define HID 256
#define NEG_SLOPE 0.2f
#define LN_EPS 1e-5f

typedef __attribute__((ext_vector_type(4))) float f32x4;
typedef __attribute__((ext_vector_type(8))) short bf16x8;
typedef __attribute__((address_space(3))) unsigned char lds_b;
typedef const __attribute__((address_space(1))) unsigned char glob_b;

__device__ __forceinline__ float bf2f_lo(unsigned int u) {
    union { unsigned int i; float f; } c; c.i = u << 16; return c.f;
}
__device__ __forceinline__ float bf2f_hi(unsigned int u) {
    union { unsigned int i; float f; } c; c.i = u & 0xffff0000u; return c.f;
}
__device__ __forceinline__ float bf2f_u(unsigned short u) {
    union { unsigned int i; float f; } c; c.i = ((unsigned int)u) << 16; return c.f;
}
__device__ __forceinline__ unsigned short f2bf(float f) {
    union { float f; unsigned int i; } c; c.f = f;
    unsigned int i = c.i;
    return (unsigned short)((i + 0x7fffu + ((i >> 16) & 1u)) >> 16);
}

// ================= k_pre: ew-sum (0..255) + hist + cvt_w + cvt_pad, one grid =================
__global__ __launch_bounds__(256) void k_pre(const float* __restrict__ ew, int E,
                                             const int* __restrict__ ei, int N, int EN, int NH,
                                             float* __restrict__ partials, int* __restrict__ deg,
                                             const float* __restrict__ W1, const float* __restrict__ W2,
                                             unsigned short* __restrict__ o1, unsigned short* __restrict__ o2, int K1,
                                             const float* __restrict__ x, unsigned short* __restrict__ x16, int FIN) {
    int t = threadIdx.x;
    int b = blockIdx.x;
    if (b < 256) {
        __shared__ float sdata[4];
        float v = 0.f;
        for (int i = b * 256 + t; i < E; i += 65536) v += ew[i];
        for (int o = 32; o; o >>= 1) v += __shfl_xor(v, o);
        if ((t & 63) == 0) sdata[t >> 6] = v;
        __syncthreads();
        if (t == 0) partials[b] = sdata[0] + sdata[1] + sdata[2] + sdata[3];
    } else if (b < 256 + NH) {
        int i = (b - 256) * 1024 + t;
        int e0 = i, e1 = i + 256, e2 = i + 512, e3 = i + 768;
        bool v0 = e0 < EN, v1 = e1 < EN, v2 = e2 < EN, v3 = e3 < EN;
        int d0 = v0 ? ((e0 < E) ? ei[E + e0] : e0 - E) : 0;
        int d1 = v1 ? ((e1 < E) ? ei[E + e1] : e1 - E) : 0;
        int d2 = v2 ? ((e2 < E) ? ei[E + e2] : e2 - E) : 0;
        int d3 = v3 ? ((e3 < E) ? ei[E + e3] : e3 - E) : 0;
        if (v0) atomicAdd(&deg[d0], 1);
        if (v1) atomicAdd(&deg[d1], 1);
        if (v2) atomicAdd(&deg[d2], 1);
        if (v3) atomicAdd(&deg[d3], 1);
    } else if (b < 256 + NH + 512) {
        int wb = b - 256 - NH;
        const float* in = (wb < 256) ? W1 : W2;
        unsigned short* out = (wb < 256) ? o1 : o2;
        int K = (wb < 256) ? K1 : 256;
        int col = wb & 255;
        float v = (t < K) ? in[(size_t)col * K + t] : 0.f;
        int ks = t >> 5, j = (t >> 3) & 3, e = t & 7;
        out[ks * 8192 + j * 2048 + ((((col << 4) ^ (j << 4))) >> 1) + e] = f2bf(v);
    } else {
        int r = b - 256 - NH - 512;
        x16[(size_t)r * 256 + t] = (t < FIN) ? f2bf(x[(size_t)r * FIN + t]) : (unsigned short)0;
    }
}

// ================= merged: per-block degree sums + sumw finish + coeff =================
__global__ __launch_bounds__(256) void k_scanred_coeff(const int* __restrict__ deg, int N, int NB,
                                                       int* __restrict__ bsum,
                                                       const float* __restrict__ partials, float* __restrict__ sumw,
                                                       const float* __restrict__ We1, const float* __restrict__ ae1,
                                                       const float* __restrict__ We2, const float* __restrict__ ae2,
                                                       float* __restrict__ c1, float* __restrict__ c2) {
    int t = threadIdx.x;
    int b = blockIdx.x;
    if (b < NB) {
        __shared__ int sdata[4];
        int i = b * 256 + t;
        int v = (i < N) ? deg[i] : 0;
        for (int o = 32; o; o >>= 1) v += __shfl_xor(v, o);
        if ((t & 63) == 0) sdata[t >> 6] = v;
        __syncthreads();
        if (t == 0) bsum[b] = sdata[0] + sdata[1] + sdata[2] + sdata[3];
    } else if (b == NB) {
        __shared__ float sdata[4];
        float v = partials[t];
        for (int o = 32; o; o >>= 1) v += __shfl_xor(v, o);
        if ((t & 63) == 0) sdata[t >> 6] = v;
        __syncthreads();
        if (t == 0) *sumw = sdata[0] + sdata[1] + sdata[2] + sdata[3];
    } else {
        float v1 = We1[t] * ae1[t];
        float v2 = We2[t] * ae2[t];
        for (int o = 1; o < 64; o <<= 1) { v1 += __shfl_xor(v1, o); v2 += __shfl_xor(v2, o); }
        if ((t & 63) == 0) { c1[t >> 6] = v1; c2[t >> 6] = v2; }
    }
}

// ================= scan_apply with inline scan of block sums =================
__global__ __launch_bounds__(256) void k_scan_apply(const int* __restrict__ deg, int N, int NB,
                                                    const int* __restrict__ bsum,
                                                    int* __restrict__ offs, int* __restrict__ cursor) {
    __shared__ int sm[256];
    __shared__ int sb[256];
    int t = threadIdx.x;
    int i = blockIdx.x * 256 + t;
    int v = (i < N) ? deg[i] : 0;
    int vb = (t < NB) ? bsum[t] : 0;
    sm[t] = v;
    sb[t] = vb;
    __syncthreads();
    for (int o = 1; o < 256; o <<= 1) {
        int tv = (t >= o) ? sm[t - o] : 0;
        int tb = (t >= o) ? sb[t - o] : 0;
        __syncthreads();
        sm[t] += tv;
        sb[t] += tb;
        __syncthreads();
    }
    int myb = bsum[blockIdx.x];
    int boff = sb[blockIdx.x] - myb;
    if (i < N) {
        int e = boff + sm[t] - v;
        offs[i] = e; cursor[i] = e;
        if (i == N - 1) offs[N] = boff + sm[t];
    }
}

// ================= gemm device body =================
__device__ __forceinline__ void gemm_dev(int bid,
    const unsigned short* __restrict__ A16, const unsigned short* __restrict__ Bt16, int M,
    const float* __restrict__ asf, const float* __restrict__ adf,
    unsigned short* __restrict__ C16, float* __restrict__ as_out, float* __restrict__ ad_out)
{
    __shared__ __align__(16) unsigned short Bsl[4 * 256 * 8]; // 16 KB
    int t = threadIdx.x;
    int lane = t & 63, w = t >> 6;
    int row0 = bid << 5;
    int kg = lane >> 4, fr = lane & 15;

    int ar0 = row0 + fr;      if (ar0 >= M) ar0 = 0;
    int ar1 = row0 + 16 + fr; if (ar1 >= M) ar1 = 0;
    const unsigned short* ap0 = A16 + (size_t)ar0 * 256 + (kg << 3);
    const unsigned short* ap1 = A16 + (size_t)ar1 * 256 + (kg << 3);

    f32x4 acc[2][4];
#pragma unroll
    for (int i = 0; i < 2; i++)
#pragma unroll
        for (int j = 0; j < 4; j++) acc[i][j] = (f32x4){0.f, 0.f, 0.f, 0.f};

    for (int ks = 0; ks < 8; ks++) {
#pragma unroll
        for (int j = 0; j < 4; j++) {
            __builtin_amdgcn_global_load_lds(
                (glob_b*)(Bt16 + (size_t)ks * 8192 + j * 2048 + t * 8),
                (lds_b*)((char*)Bsl + j * 4096 + t * 16),
                16, 0, 0);
        }
        bf16x8 a0 = *(const bf16x8*)(ap0 + (ks << 5));
        bf16x8 a1 = *(const bf16x8*)(ap1 + (ks << 5));
        __syncthreads();
#pragma unroll
        for (int nf = 0; nf < 4; nf++) {
            int col = (w << 6) + (nf << 4) + fr;
            bf16x8 bv = *(const bf16x8*)((const char*)Bsl + (kg << 12) + (((col << 4)) ^ (kg << 4)));
            acc[0][nf] = __builtin_amdgcn_mfma_f32_16x16x32_bf16(a0, bv, acc[0][nf], 0, 0, 0);
            acc[1][nf] = __builtin_amdgcn_mfma_f32_16x16x32_bf16(a1, bv, acc[1][nf], 0, 0, 0);
        }
        __syncthreads();
    }

#pragma unroll
    for (int mf = 0; mf < 2; mf++)
#pragma unroll
        for (int j = 0; j < 4; j++) {
            int gr = row0 + mf * 16 + kg * 4 + j;
            if (gr < M) {
#pragma unroll
                for (int nf = 0; nf < 4; nf++)
                    C16[(size_t)gr * 256 + (w << 6) + (nf << 4) + fr] = f2bf(acc[mf][nf][j]);
            }
        }
    float asv[4], adv[4];
#pragma unroll
    for (int nf = 0; nf < 4; nf++) {
        int col = (w << 6) + (nf << 4) + fr;
        asv[nf] = asf[col]; adv[nf] = adf[col];
    }
#pragma unroll
    for (int mf = 0; mf < 2; mf++)
#pragma unroll
        for (int j = 0; j < 4; j++) {
            float ps = acc[mf][0][j] * asv[0] + acc[mf][1][j] * asv[1] + acc[mf][2][j] * asv[2] + acc[mf][3][j] * asv[3];
            float pd = acc[mf][0][j] * adv[0] + acc[mf][1][j] * adv[1] + acc[mf][2][j] * adv[2] + acc[mf][3][j] * adv[3];
#pragma unroll
            for (int o = 1; o < 16; o <<= 1) { ps += __shfl_xor(ps, o); pd += __shfl_xor(pd, o); }
            if (fr == 0) {
                int gr = row0 + mf * 16 + kg * 4 + j;
                if (gr < M) {
                    as_out[gr * 4 + w] = ps;
                    ad_out[gr * 4 + w] = pd;
                }
            }
        }
}

// ================= merged: scatter (blocks [0,NSc)) + gemm layer-1 (blocks [NSc,NSc+MB)) =================
// Independent: scatter needs cursor (done); gemm needs x16/w1 (done). Scatter latency hides under gemm.
__global__ __launch_bounds__(256) void k_scatter_gemm(int NSc, const int* __restrict__ ei, int E, int EN,
                                                      int* __restrict__ cursor, int* __restrict__ csr_eid,
                                                      const unsigned short* __restrict__ A16,
                                                      const unsigned short* __restrict__ Bt16, int M,
                                                      const float* __restrict__ asf, const float* __restrict__ adf,
                                                      unsigned short* __restrict__ C16,
                                                      float* __restrict__ as_out, float* __restrict__ ad_out) {
    int b = blockIdx.x;
    if (b < NSc) {
        int i = b * 1024 + threadIdx.x;
        int e0 = i, e1 = i + 256, e2 = i + 512, e3 = i + 768;
        bool v0 = e0 < EN, v1 = e1 < EN, v2 = e2 < EN, v3 = e3 < EN;
        int d0 = v0 ? ((e0 < E) ? ei[E + e0] : e0 - E) : 0;
        int d1 = v1 ? ((e1 < E) ? ei[E + e1] : e1 - E) : 0;
        int d2 = v2 ? ((e2 < E) ? ei[E + e2] : e2 - E) : 0;
        int d3 = v3 ? ((e3 < E) ? ei[E + e3] : e3 - E) : 0;
        int p0 = v0 ? atomicAdd(&cursor[d0], 1) : 0;
        int p1 = v1 ? atomicAdd(&cursor[d1], 1) : 0;
        int p2 = v2 ? atomicAdd(&cursor[d2], 1) : 0;
        int p3 = v3 ? atomicAdd(&cursor[d3], 1) : 0;
        if (v0) csr_eid[p0] = e0;
        if (v1) csr_eid[p1] = e1;
        if (v2) csr_eid[p2] = e2;
        if (v3) csr_eid[p3] = e3;
    } else {
        gemm_dev(b - NSc, A16, Bt16, M, asf, adf, C16, as_out, ad_out);
    }
}

// ================= standalone gemm (layer 2) =================
__global__ __launch_bounds__(256) void gemm_mfma(
    const unsigned short* __restrict__ A16, const unsigned short* __restrict__ Bt16, int M,
    const float* __restrict__ asf, const float* __restrict__ adf,
    unsigned short* __restrict__ C16, float* __restrict__ as_out, float* __restrict__ ad_out) {
    gemm_dev(blockIdx.x, A16, Bt16, M, asf, adf, C16, as_out, ad_out);
}

// ================= fused GAT + bias + LN + ELU -> bf16 out =================
// BUILD=1: sort this node's eids in-register (rank + ds_permute), gather ei/ew inline,
//          persist csr_src/csr_w for the BUILD=0 pass. Deterministic (sorted by eid).
#define ACC8(u, q) do { \
    acc0 += (q) * bf2f_lo((u).x); acc1 += (q) * bf2f_hi((u).x); \
    acc2 += (q) * bf2f_lo((u).y); acc3 += (q) * bf2f_hi((u).y); \
    acc4 += (q) * bf2f_lo((u).z); acc5 += (q) * bf2f_hi((u).z); \
    acc6 += (q) * bf2f_lo((u).w); acc7 += (q) * bf2f_hi((u).w); } while (0)

template<int BUILD>
__global__ __launch_bounds__(256) void gat_kernel(
    const unsigned short* __restrict__ xp16, const int* __restrict__ offs,
    int* __restrict__ csr_eid, const int* __restrict__ ei, const float* __restrict__ ew,
    const float* __restrict__ sumw, int E,
    int* __restrict__ csr_src, float* __restrict__ csr_w,
    const float* __restrict__ as_, const float* __restrict__ ad_,
    const float* __restrict__ cvec, const float* __restrict__ bias,
    const float* __restrict__ ln_g, const float* __restrict__ ln_b,
    int N, unsigned short* __restrict__ out16) {
    __shared__ float p_lds[4][256];
    __shared__ int   s_lds[4][64];
    int lane = threadIdx.x & 63;
    int wid = threadIdx.x >> 6;
    int n = (blockIdx.x << 2) + wid;
    if (n >= N) return;
    int start = offs[n], end = offs[n + 1];
    int dtot = end - start;
    float wfill = 0.f;
    if (BUILD) {
        wfill = *sumw / (float)E;
        if (dtot > 64) {    // cold path (P ~ 0 for this graph): pre-sort globally
            if (lane == 0) {
                for (int i = start + 1; i < end; i++) {
                    int ke = csr_eid[i];
                    int j = i - 1;
                    while (j >= start && csr_eid[j] > ke) { csr_eid[j + 1] = csr_eid[j]; j--; }
                    csr_eid[j + 1] = ke;
                }
            }
            __threadfence();
        }
    }
    int e0 = lane >> 5;
    int colb = lane & 31;
    int hq2 = colb >> 3;
    const unsigned short* xbase = xp16 + (size_t)colb * 8;
    float4 adv = *(const float4*)(ad_ + (size_t)n * 4);
    float c0 = cvec[0], c1 = cvec[1], c2 = cvec[2], c3 = cvec[3];
    float m = -INFINITY, dn = 0.f;
    float acc0 = 0, acc1 = 0, acc2 = 0, acc3 = 0, acc4 = 0, acc5 = 0, acc6 = 0, acc7 = 0;

    for (int base = start; base < end; base += 64) {
        int idx = base + lane;
        bool act = idx < end;
        int cnt = end - base; if (cnt > 64) cnt = 64;
        int s; float w;
        if (BUILD) {
            int key = act ? csr_eid[idx] : 0x7fffffff;
            if (dtot <= 64) {
                int rank = 0;
                for (int j = 0; j < cnt; j++) {
                    int kj = __shfl(key, j);
                    rank += (kj < key) ? 1 : 0;
                }
                key = __builtin_amdgcn_ds_permute(rank << 2, key);
            }
            if (act) {
                if (key < E) { s = ei[key]; w = ew[key]; }
                else         { s = key - E; w = wfill; }
                csr_src[idx] = s;
                csr_w[idx] = w;
            } else { s = 0; w = 0.f; }
        } else {
            s = act ? csr_src[idx] : 0;
            w = act ? csr_w[idx] : 0.f;
        }
        float4 av = *(const float4*)(as_ + (size_t)s * 4);
        float l0 = av.x + adv.x + w * c0; l0 = l0 >= 0.f ? l0 : NEG_SLOPE * l0;
        float l1 = av.y + adv.y + w * c1; l1 = l1 >= 0.f ? l1 : NEG_SLOPE * l1;
        float l2 = av.z + adv.z + w * c2; l2 = l2 >= 0.f ? l2 : NEG_SLOPE * l2;
        float l3 = av.w + adv.w + w * c3; l3 = l3 >= 0.f ? l3 : NEG_SLOPE * l3;
        float lm = fmaxf(fmaxf(l0, l1), fmaxf(l2, l3));
        if (!act) lm = -INFINITY;
        for (int o = 32; o; o >>= 1) lm = fmaxf(lm, __shfl_xor(lm, o));
        float nm = fmaxf(m, lm);
        float sc = __expf(m - nm);
        m = nm;
        dn *= sc;
        acc0 *= sc; acc1 *= sc; acc2 *= sc; acc3 *= sc;
        acc4 *= sc; acc5 *= sc; acc6 *= sc; acc7 *= sc;
        float p0 = act ? __expf(l0 - m) : 0.f;
        float p1 = act ? __expf(l1 - m) : 0.f;
        float p2 = act ? __expf(l2 - m) : 0.f;
        float p3 = act ? __expf(l3 - m) : 0.f;
        float4 pv = { p0, p1, p2, p3 };
        *(float4*)&p_lds[wid][lane << 2] = pv;
        s_lds[wid][lane] = s;
        int k = 0;
        for (; k + 8 <= cnt; k += 8) {
            int i0 = k + e0, i1 = k + 2 + e0, i2 = k + 4 + e0, i3 = k + 6 + e0;
            int s0 = s_lds[wid][i0], s1 = s_lds[wid][i1], s2 = s_lds[wid][i2], s3 = s_lds[wid][i3];
            uint4 u0 = *(const uint4*)(xbase + (size_t)s0 * 256);
            uint4 u1 = *(const uint4*)(xbase + (size_t)s1 * 256);
            uint4 u2 = *(const uint4*)(xbase + (size_t)s2 * 256);
            uint4 u3 = *(const uint4*)(xbase + (size_t)s3 * 256);
            float q0 = p_lds[wid][(i0 << 2) + hq2];
            float q1 = p_lds[wid][(i1 << 2) + hq2];
            float q2 = p_lds[wid][(i2 << 2) + hq2];
            float q3 = p_lds[wid][(i3 << 2) + hq2];
            dn += q0 + q1 + q2 + q3;
            ACC8(u0, q0); ACC8(u1, q1); ACC8(u2, q2); ACC8(u3, q3);
        }
        for (; k < cnt; k += 2) {
            int i = k + e0;
            bool v = i < cnt;
            int si = s_lds[wid][v ? i : 0];
            float qi = v ? p_lds[wid][(i << 2) + hq2] : 0.f;
            uint4 u = *(const uint4*)(xbase + (size_t)si * 256);
            dn += qi;
            ACC8(u, qi);
        }
    }
    acc0 += __shfl_xor(acc0, 32); acc1 += __shfl_xor(acc1, 32);
    acc2 += __shfl_xor(acc2, 32); acc3 += __shfl_xor(acc3, 32);
    acc4 += __shfl_xor(acc4, 32); acc5 += __shfl_xor(acc5, 32);
    acc6 += __shfl_xor(acc6, 32); acc7 += __shfl_xor(acc7, 32);
    dn += __shfl_xor(dn, 32);
    float inv = 1.f / dn;
    int cb8 = colb << 3;
    float4 bA = *(const float4*)(bias + cb8);
    float4 bB = *(const float4*)(bias + cb8 + 4);
    float o0 = acc0 * inv + bA.x, o1 = acc1 * inv + bA.y, o2 = acc2 * inv + bA.z, o3 = acc3 * inv + bA.w;
    float o4 = acc4 * inv + bB.x, o5 = acc5 * inv + bB.y, o6 = acc6 * inv + bB.z, o7 = acc7 * inv + bB.w;
    float part = ((o0 + o1) + (o2 + o3)) + ((o4 + o5) + (o6 + o7));
    for (int o = 16; o; o >>= 1) part += __shfl_xor(part, o);
    float mu = part * (1.f / 256.f);
    float d0 = o0 - mu, d1 = o1 - mu, d2 = o2 - mu, d3 = o3 - mu;
    float d4 = o4 - mu, d5 = o5 - mu, d6 = o6 - mu, d7 = o7 - mu;
    float vpart = ((d0 * d0 + d1 * d1) + (d2 * d2 + d3 * d3)) + ((d4 * d4 + d5 * d5) + (d6 * d6 + d7 * d7));
    for (int o = 16; o; o >>= 1) vpart += __shfl_xor(vpart, o);
    float rstd = rsqrtf(vpart * (1.f / 256.f) + LN_EPS);
    float4 gA = *(const float4*)(ln_g + cb8), gB = *(const float4*)(ln_g + cb8 + 4);
    float4 eA = *(const float4*)(ln_b + cb8), eB = *(const float4*)(ln_b + cb8 + 4);
    float y0 = d0 * rstd * gA.x + eA.x; y0 = y0 > 0.f ? y0 : __expf(y0) - 1.f;
    float y1 = d1 * rstd * gA.y + eA.y; y1 = y1 > 0.f ? y1 : __expf(y1) - 1.f;
    float y2 = d2 * rstd * gA.z + eA.z; y2 = y2 > 0.f ? y2 : __expf(y2) - 1.f;
    float y3 = d3 * rstd * gA.w + eA.w; y3 = y3 > 0.f ? y3 : __expf(y3) - 1.f;
    float y4 = d4 * rstd * gB.x + eB.x; y4 = y4 > 0.f ? y4 : __expf(y4) - 1.f;
    float y5 = d5 * rstd * gB.y + eB.y; y5 = y5 > 0.f ? y5 : __expf(y5) - 1.f;
    float y6 = d6 * rstd * gB.z + eB.z; y6 = y6 > 0.f ? y6 : __expf(y6) - 1.f;
    float y7 = d7 * rstd * gB.w + eB.w; y7 = y7 > 0.f ? y7 : __expf(y7) - 1.f;
    if (lane < 32) {
        uint4 ov;
        ov.x = ((unsigned int)f2bf(y1) << 16) | f2bf(y0);
        ov.y = ((unsigned int)f2bf(y3) << 16) | f2bf(y2);
        ov.z = ((unsigned int)f2bf(y5) << 16) | f2bf(y4);
        ov.w = ((unsigned int)f2bf(y7) << 16) | f2bf(y6);
        *(uint4*)(out16 + (size_t)n * HID + cb8) = ov;
    }
}

// ================= batch mean pool (bf16 input), 4-way unrolled =================
__device__ __forceinline__ int lower_bound_i(const int* a, int n, int key) {
    int lo = 0, hi = n;
    while (lo < hi) { int mid = (lo + hi) >> 1; if (a[mid] < key) lo = mid + 1; else hi = mid; }
    return lo;
}

__global__ __launch_bounds__(256) void pool_kernel(const unsigned short* __restrict__ h, const int* __restrict__ batch,
                                                   int N, float* __restrict__ out) {
    int b = blockIdx.x;
    int lo = lower_bound_i(batch, N, b);
    int hi = lower_bound_i(batch, N, b + 1);
    float a0 = 0.f, a1 = 0.f, a2 = 0.f, a3 = 0.f;
    int n = lo;
    for (; n + 4 <= hi; n += 4) {
        a0 += bf2f_u(h[(size_t)(n + 0) * HID + threadIdx.x]);
        a1 += bf2f_u(h[(size_t)(n + 1) * HID + threadIdx.x]);
        a2 += bf2f_u(h[(size_t)(n + 2) * HID + threadIdx.x]);
        a3 += bf2f_u(h[(size_t)(n + 3) * HID + threadIdx.x]);
    }
    for (; n < hi; n++) a0 += bf2f_u(h[(size_t)n * HID + threadIdx.x]);
    float acc = (a0 + a1) + (a2 + a3);
    out[(size_t)b * HID + threadIdx.x] = acc / fmaxf((float)(hi - lo), 1.f);
}

extern "C" void kernel_launch(void* const* d_in, const int* in_sizes, int n_in,
                              void* d_out, int out_size, void* d_ws, size_t ws_size,
                              hipStream_t stream) {
    const float* x    = (const float*)d_in[0];
    const int*   ei   = (const int*)d_in[1];
    const float* ew   = (const float*)d_in[2];
    const int*   batch= (const int*)d_in[3];
    const float* W1   = (const float*)d_in[4];
    const float* as1  = (const float*)d_in[5];
    const float* ad1  = (const float*)d_in[6];
    const float* ae1  = (const float*)d_in[7];
    const float* We1  = (const float*)d_in[8];
    const float* b1   = (const float*)d_in[9];
    const float* W2   = (const float*)d_in[10];
    const float* as2  = (const float*)d_in[11];
    const float* ad2  = (const float*)d_in[12];
    const float* ae2  = (const float*)d_in[13];
    const float* We2  = (const float*)d_in[14];
    const float* b2   = (const float*)d_in[15];
    const float* ln1g = (const float*)d_in[16];
    const float* ln1b = (const float*)d_in[17];
    const float* ln2g = (const float*)d_in[18];
    const float* ln2b = (const float*)d_in[19];

    int N = in_sizes[3];
    int E = in_sizes[2];
    int FIN = in_sizes[0] / N;
    int EN = E + N;
    int B = out_size / HID;
    float* outp = (float*)d_out;
    int NB = (N + 255) / 256;          // <= 256 required (N=50000 -> 196)
    int NH = (EN + 1023) / 1024;       // 4-edge-ILP hist blocks
    int NSc = (EN + 1023) / 1024;      // scatter blocks

    char* ws = (char*)d_ws;
    size_t off = 0;
    auto alloc = [&](size_t bytes) { void* p = ws + off; off = (off + bytes + 255) & ~(size_t)255; return p; };
    float* sumw    = (float*)alloc(4);
    int*   deg     = (int*)  alloc((size_t)N * 4);           // zeroed region = [0, 256 + N*4)
    size_t zero_bytes = 256 + (size_t)N * 4;
    float* partials= (float*)alloc(256 * 4);
    int*   bsum    = (int*)  alloc(256 * 4);
    int*   offs    = (int*)  alloc((size_t)(N + 1) * 4);
    int*   cursor  = (int*)  alloc((size_t)N * 4);
    int*   csr_eid = (int*)  alloc((size_t)EN * 4);
    int*   csr_src = (int*)  alloc((size_t)EN * 4);
    float* csr_w   = (float*)alloc((size_t)EN * 4);
    float* asb     = (float*)alloc((size_t)N * 4 * 4);
    float* adb     = (float*)alloc((size_t)N * 4 * 4);
    float* cc      = (float*)alloc(64);
    unsigned short* w1_16 = (unsigned short*)alloc((size_t)HID * HID * 2);
    unsigned short* w2_16 = (unsigned short*)alloc((size_t)HID * HID * 2);
    unsigned short* x16   = (unsigned short*)alloc((size_t)N * HID * 2);  // x -> h1 -> h2 (reused)
    unsigned short* xp16  = (unsigned short*)alloc((size_t)N * HID * 2);
    (void)ws_size; (void)n_in;

    int MB = (N + 31) / 32;

    (void)hipMemsetAsync(d_ws, 0, zero_bytes, stream);
    k_pre<<<256 + NH + 512 + N, 256, 0, stream>>>(ew, E, ei, N, EN, NH, partials, deg,
                                                  W1, W2, w1_16, w2_16, FIN, x, x16, FIN);
    k_scanred_coeff<<<NB + 2, 256, 0, stream>>>(deg, N, NB, bsum, partials, sumw, We1, ae1, We2, ae2, cc, cc + 4);
    k_scan_apply<<<NB, 256, 0, stream>>>(deg, N, NB, bsum, offs, cursor);
    // scatter || layer-1 gemm (independent; scatter hides under gemm)
    k_scatter_gemm<<<NSc + MB, 256, 0, stream>>>(NSc, ei, E, EN, cursor, csr_eid,
                                                 x16, w1_16, N, as1, ad1, xp16, asb, adb);
    // layer-1 gat: builds sorted csr inline, persists for layer 2
    gat_kernel<1><<<(N + 3) / 4, 256, 0, stream>>>(xp16, offs, csr_eid, ei, ew, sumw, E, csr_src, csr_w,
                                                   asb, adb, cc, b1, ln1g, ln1b, N, x16);
    // layer 2
    gemm_mfma<<<MB, 256, 0, stream>>>(x16, w2_16, N, as2, ad2, xp16, asb, adb);
    gat_kernel<0><<<(N + 3) / 4, 256, 0, stream>>>(xp16, offs, csr_eid, ei, ew, sumw, E, csr_src, csr_w,
                                                   asb, adb, cc + 4, b2, ln2g, ln2b, N, x16);
    // pool
    pool_kernel<<<B, 256, 0, stream>>>(x16, batch, N, outp);
}

// Round 16
// 349.094 us; speedup vs baseline: 1.0244x; 1.0244x over previous
//
#include <hip/hip_runtime.h>
#include <math.h>

#define HID 256
#define NEG_SLOPE 0.2f
#define LN_EPS 1e-5f

typedef __attribute__((ext_vector_type(4))) float f32x4;
typedef __attribute__((ext_vector_type(8))) short bf16x8;
typedef __attribute__((address_space(3))) unsigned char lds_b;
typedef const __attribute__((address_space(1))) unsigned char glob_b;

__device__ __forceinline__ float bf2f_lo(unsigned int u) {
    union { unsigned int i; float f; } c; c.i = u << 16; return c.f;
}
__device__ __forceinline__ float bf2f_hi(unsigned int u) {
    union { unsigned int i; float f; } c; c.i = u & 0xffff0000u; return c.f;
}
__device__ __forceinline__ float bf2f_u(unsigned short u) {
    union { unsigned int i; float f; } c; c.i = ((unsigned int)u) << 16; return c.f;
}
__device__ __forceinline__ unsigned short f2bf(float f) {
    union { float f; unsigned int i; } c; c.f = f;
    unsigned int i = c.i;
    return (unsigned short)((i + 0x7fffu + ((i >> 16) & 1u)) >> 16);
}

// ================= k_pre: ew-sum (0..255) + hist + cvt_w + cvt_pad, one grid =================
__global__ __launch_bounds__(256) void k_pre(const float* __restrict__ ew, int E,
                                             const int* __restrict__ ei, int N, int EN, int NH,
                                             float* __restrict__ partials, int* __restrict__ deg,
                                             const float* __restrict__ W1, const float* __restrict__ W2,
                                             unsigned short* __restrict__ o1, unsigned short* __restrict__ o2, int K1,
                                             const float* __restrict__ x, unsigned short* __restrict__ x16, int FIN) {
    int t = threadIdx.x;
    int b = blockIdx.x;
    if (b < 256) {
        __shared__ float sdata[4];
        float v = 0.f;
        for (int i = b * 256 + t; i < E; i += 65536) v += ew[i];
        for (int o = 32; o; o >>= 1) v += __shfl_xor(v, o);
        if ((t & 63) == 0) sdata[t >> 6] = v;
        __syncthreads();
        if (t == 0) partials[b] = sdata[0] + sdata[1] + sdata[2] + sdata[3];
    } else if (b < 256 + NH) {
        int i = (b - 256) * 1024 + t;
        int e0 = i, e1 = i + 256, e2 = i + 512, e3 = i + 768;
        bool v0 = e0 < EN, v1 = e1 < EN, v2 = e2 < EN, v3 = e3 < EN;
        int d0 = v0 ? ((e0 < E) ? ei[E + e0] : e0 - E) : 0;
        int d1 = v1 ? ((e1 < E) ? ei[E + e1] : e1 - E) : 0;
        int d2 = v2 ? ((e2 < E) ? ei[E + e2] : e2 - E) : 0;
        int d3 = v3 ? ((e3 < E) ? ei[E + e3] : e3 - E) : 0;
        if (v0) atomicAdd(&deg[d0], 1);
        if (v1) atomicAdd(&deg[d1], 1);
        if (v2) atomicAdd(&deg[d2], 1);
        if (v3) atomicAdd(&deg[d3], 1);
    } else if (b < 256 + NH + 512) {
        int wb = b - 256 - NH;
        const float* in = (wb < 256) ? W1 : W2;
        unsigned short* out = (wb < 256) ? o1 : o2;
        int K = (wb < 256) ? K1 : 256;
        int col = wb & 255;
        float v = (t < K) ? in[(size_t)col * K + t] : 0.f;
        int ks = t >> 5, j = (t >> 3) & 3, e = t & 7;
        out[ks * 8192 + j * 2048 + ((((col << 4) ^ (j << 4))) >> 1) + e] = f2bf(v);
    } else {
        int r = b - 256 - NH - 512;
        x16[(size_t)r * 256 + t] = (t < FIN) ? f2bf(x[(size_t)r * FIN + t]) : (unsigned short)0;
    }
}

// ================= merged: per-block degree sums + sumw finish + coeff =================
__global__ __launch_bounds__(256) void k_scanred_coeff(const int* __restrict__ deg, int N, int NB,
                                                       int* __restrict__ bsum,
                                                       const float* __restrict__ partials, float* __restrict__ sumw,
                                                       const float* __restrict__ We1, const float* __restrict__ ae1,
                                                       const float* __restrict__ We2, const float* __restrict__ ae2,
                                                       float* __restrict__ c1, float* __restrict__ c2) {
    int t = threadIdx.x;
    int b = blockIdx.x;
    if (b < NB) {
        __shared__ int sdata[4];
        int i = b * 256 + t;
        int v = (i < N) ? deg[i] : 0;
        for (int o = 32; o; o >>= 1) v += __shfl_xor(v, o);
        if ((t & 63) == 0) sdata[t >> 6] = v;
        __syncthreads();
        if (t == 0) bsum[b] = sdata[0] + sdata[1] + sdata[2] + sdata[3];
    } else if (b == NB) {
        __shared__ float sdata[4];
        float v = partials[t];
        for (int o = 32; o; o >>= 1) v += __shfl_xor(v, o);
        if ((t & 63) == 0) sdata[t >> 6] = v;
        __syncthreads();
        if (t == 0) *sumw = sdata[0] + sdata[1] + sdata[2] + sdata[3];
    } else {
        float v1 = We1[t] * ae1[t];
        float v2 = We2[t] * ae2[t];
        for (int o = 1; o < 64; o <<= 1) { v1 += __shfl_xor(v1, o); v2 += __shfl_xor(v2, o); }
        if ((t & 63) == 0) { c1[t >> 6] = v1; c2[t >> 6] = v2; }
    }
}

// ================= scan_apply with inline scan of block sums =================
__global__ __launch_bounds__(256) void k_scan_apply(const int* __restrict__ deg, int N, int NB,
                                                    const int* __restrict__ bsum,
                                                    int* __restrict__ offs, int* __restrict__ cursor) {
    __shared__ int sm[256];
    __shared__ int sb[256];
    int t = threadIdx.x;
    int i = blockIdx.x * 256 + t;
    int v = (i < N) ? deg[i] : 0;
    int vb = (t < NB) ? bsum[t] : 0;
    sm[t] = v;
    sb[t] = vb;
    __syncthreads();
    for (int o = 1; o < 256; o <<= 1) {
        int tv = (t >= o) ? sm[t - o] : 0;
        int tb = (t >= o) ? sb[t - o] : 0;
        __syncthreads();
        sm[t] += tv;
        sb[t] += tb;
        __syncthreads();
    }
    int myb = bsum[blockIdx.x];
    int boff = sb[blockIdx.x] - myb;
    if (i < N) {
        int e = boff + sm[t] - v;
        offs[i] = e; cursor[i] = e;
        if (i == N - 1) offs[N] = boff + sm[t];
    }
}

// ================= gemm device body =================
__device__ __forceinline__ void gemm_dev(int bid,
    const unsigned short* __restrict__ A16, const unsigned short* __restrict__ Bt16, int M,
    const float* __restrict__ asf, const float* __restrict__ adf,
    unsigned short* __restrict__ C16, float* __restrict__ as_out, float* __restrict__ ad_out)
{
    __shared__ __align__(16) unsigned short Bsl[4 * 256 * 8]; // 16 KB
    int t = threadIdx.x;
    int lane = t & 63, w = t >> 6;
    int row0 = bid << 5;
    int kg = lane >> 4, fr = lane & 15;

    int ar0 = row0 + fr;      if (ar0 >= M) ar0 = 0;
    int ar1 = row0 + 16 + fr; if (ar1 >= M) ar1 = 0;
    const unsigned short* ap0 = A16 + (size_t)ar0 * 256 + (kg << 3);
    const unsigned short* ap1 = A16 + (size_t)ar1 * 256 + (kg << 3);

    f32x4 acc[2][4];
#pragma unroll
    for (int i = 0; i < 2; i++)
#pragma unroll
        for (int j = 0; j < 4; j++) acc[i][j] = (f32x4){0.f, 0.f, 0.f, 0.f};

    for (int ks = 0; ks < 8; ks++) {
#pragma unroll
        for (int j = 0; j < 4; j++) {
            __builtin_amdgcn_global_load_lds(
                (glob_b*)(Bt16 + (size_t)ks * 8192 + j * 2048 + t * 8),
                (lds_b*)((char*)Bsl + j * 4096 + t * 16),
                16, 0, 0);
        }
        bf16x8 a0 = *(const bf16x8*)(ap0 + (ks << 5));
        bf16x8 a1 = *(const bf16x8*)(ap1 + (ks << 5));
        __syncthreads();
#pragma unroll
        for (int nf = 0; nf < 4; nf++) {
            int col = (w << 6) + (nf << 4) + fr;
            bf16x8 bv = *(const bf16x8*)((const char*)Bsl + (kg << 12) + (((col << 4)) ^ (kg << 4)));
            acc[0][nf] = __builtin_amdgcn_mfma_f32_16x16x32_bf16(a0, bv, acc[0][nf], 0, 0, 0);
            acc[1][nf] = __builtin_amdgcn_mfma_f32_16x16x32_bf16(a1, bv, acc[1][nf], 0, 0, 0);
        }
        __syncthreads();
    }

#pragma unroll
    for (int mf = 0; mf < 2; mf++)
#pragma unroll
        for (int j = 0; j < 4; j++) {
            int gr = row0 + mf * 16 + kg * 4 + j;
            if (gr < M) {
#pragma unroll
                for (int nf = 0; nf < 4; nf++)
                    C16[(size_t)gr * 256 + (w << 6) + (nf << 4) + fr] = f2bf(acc[mf][nf][j]);
            }
        }
    float asv[4], adv[4];
#pragma unroll
    for (int nf = 0; nf < 4; nf++) {
        int col = (w << 6) + (nf << 4) + fr;
        asv[nf] = asf[col]; adv[nf] = adf[col];
    }
#pragma unroll
    for (int mf = 0; mf < 2; mf++)
#pragma unroll
        for (int j = 0; j < 4; j++) {
            float ps = acc[mf][0][j] * asv[0] + acc[mf][1][j] * asv[1] + acc[mf][2][j] * asv[2] + acc[mf][3][j] * asv[3];
            float pd = acc[mf][0][j] * adv[0] + acc[mf][1][j] * adv[1] + acc[mf][2][j] * adv[2] + acc[mf][3][j] * adv[3];
#pragma unroll
            for (int o = 1; o < 16; o <<= 1) { ps += __shfl_xor(ps, o); pd += __shfl_xor(pd, o); }
            if (fr == 0) {
                int gr = row0 + mf * 16 + kg * 4 + j;
                if (gr < M) {
                    as_out[gr * 4 + w] = ps;
                    ad_out[gr * 4 + w] = pd;
                }
            }
        }
}

// ================= merged: scatter (blocks [0,NSc)) + gemm layer-1 =================
__global__ __launch_bounds__(256) void k_scatter_gemm(int NSc, const int* __restrict__ ei, int E, int EN,
                                                      int* __restrict__ cursor, int* __restrict__ csr_eid,
                                                      const unsigned short* __restrict__ A16,
                                                      const unsigned short* __restrict__ Bt16, int M,
                                                      const float* __restrict__ asf, const float* __restrict__ adf,
                                                      unsigned short* __restrict__ C16,
                                                      float* __restrict__ as_out, float* __restrict__ ad_out) {
    int b = blockIdx.x;
    if (b < NSc) {
        int i = b * 1024 + threadIdx.x;
        int e0 = i, e1 = i + 256, e2 = i + 512, e3 = i + 768;
        bool v0 = e0 < EN, v1 = e1 < EN, v2 = e2 < EN, v3 = e3 < EN;
        int d0 = v0 ? ((e0 < E) ? ei[E + e0] : e0 - E) : 0;
        int d1 = v1 ? ((e1 < E) ? ei[E + e1] : e1 - E) : 0;
        int d2 = v2 ? ((e2 < E) ? ei[E + e2] : e2 - E) : 0;
        int d3 = v3 ? ((e3 < E) ? ei[E + e3] : e3 - E) : 0;
        int p0 = v0 ? atomicAdd(&cursor[d0], 1) : 0;
        int p1 = v1 ? atomicAdd(&cursor[d1], 1) : 0;
        int p2 = v2 ? atomicAdd(&cursor[d2], 1) : 0;
        int p3 = v3 ? atomicAdd(&cursor[d3], 1) : 0;
        if (v0) csr_eid[p0] = e0;
        if (v1) csr_eid[p1] = e1;
        if (v2) csr_eid[p2] = e2;
        if (v3) csr_eid[p3] = e3;
    } else {
        gemm_dev(b - NSc, A16, Bt16, M, asf, adf, C16, as_out, ad_out);
    }
}

// ================= standalone sort_gather (wave-per-node rank sort + payload gather) =================
__global__ __launch_bounds__(256) void k_sort_gather(const int* __restrict__ offs, int* __restrict__ eid,
                                                     const int* __restrict__ ei, const float* __restrict__ ew,
                                                     const float* __restrict__ sumw, int E, int N,
                                                     int* __restrict__ csr_src, float* __restrict__ csr_w) {
    int lane = threadIdx.x & 63;
    int n = (blockIdx.x << 2) + (threadIdx.x >> 6);
    if (n >= N) return;
    int s0 = offs[n];
    int d = offs[n + 1] - s0;
    if (d <= 0) return;
    if (d <= 64) {
        int key = (lane < d) ? eid[s0 + lane] : 0x7fffffff;
        int rank = 0;
        for (int j = 0; j < d; j++) {
            int kj = __shfl(key, j);
            rank += (kj < key) ? 1 : 0;
        }
        if (lane < d) {
            int s; float wv;
            if (key < E) { s = ei[key]; wv = ew[key]; }
            else         { s = key - E; wv = *sumw / (float)E; }
            csr_src[s0 + rank] = s;
            csr_w[s0 + rank] = wv;
        }
    } else {
        if (lane == 0) {
            for (int i = s0 + 1; i < s0 + d; i++) {
                int ke = eid[i];
                int j = i - 1;
                while (j >= s0 && eid[j] > ke) { eid[j + 1] = eid[j]; j--; }
                eid[j + 1] = ke;
            }
        }
        __builtin_amdgcn_wave_barrier();
        for (int i = lane; i < d; i += 64) {
            int e = eid[s0 + i];
            int s; float wv;
            if (e < E) { s = ei[e]; wv = ew[e]; }
            else       { s = e - E; wv = *sumw / (float)E; }
            csr_src[s0 + i] = s;
            csr_w[s0 + i] = wv;
        }
    }
}

// ================= standalone gemm (layer 2) =================
__global__ __launch_bounds__(256) void gemm_mfma(
    const unsigned short* __restrict__ A16, const unsigned short* __restrict__ Bt16, int M,
    const float* __restrict__ asf, const float* __restrict__ adf,
    unsigned short* __restrict__ C16, float* __restrict__ as_out, float* __restrict__ ad_out) {
    gemm_dev(blockIdx.x, A16, Bt16, M, asf, adf, C16, as_out, ad_out);
}

// ================= fused GAT + bias + LN + ELU -> bf16 out (round-14 form) =================
#define ACC8(u, q) do { \
    acc0 += (q) * bf2f_lo((u).x); acc1 += (q) * bf2f_hi((u).x); \
    acc2 += (q) * bf2f_lo((u).y); acc3 += (q) * bf2f_hi((u).y); \
    acc4 += (q) * bf2f_lo((u).z); acc5 += (q) * bf2f_hi((u).z); \
    acc6 += (q) * bf2f_lo((u).w); acc7 += (q) * bf2f_hi((u).w); } while (0)

__global__ __launch_bounds__(256) void gat_kernel(
    const unsigned short* __restrict__ xp16, const int* __restrict__ offs,
    const int* __restrict__ csr_src, const float* __restrict__ csr_w,
    const float* __restrict__ as_, const float* __restrict__ ad_,
    const float* __restrict__ cvec, const float* __restrict__ bias,
    const float* __restrict__ ln_g, const float* __restrict__ ln_b,
    int N, unsigned short* __restrict__ out16) {
    __shared__ float p_lds[4][256];
    __shared__ int   s_lds[4][64];
    int lane = threadIdx.x & 63;
    int wid = threadIdx.x >> 6;
    int n = (blockIdx.x << 2) + wid;
    if (n >= N) return;
    int start = offs[n], end = offs[n + 1];
    int e0 = lane >> 5;
    int colb = lane & 31;
    int hq2 = colb >> 3;
    const unsigned short* xbase = xp16 + (size_t)colb * 8;
    float4 adv = *(const float4*)(ad_ + (size_t)n * 4);
    float c0 = cvec[0], c1 = cvec[1], c2 = cvec[2], c3 = cvec[3];
    float m = -INFINITY, dn = 0.f;
    float acc0 = 0, acc1 = 0, acc2 = 0, acc3 = 0, acc4 = 0, acc5 = 0, acc6 = 0, acc7 = 0;

    for (int base = start; base < end; base += 64) {
        int idx = base + lane;
        bool act = idx < end;
        int s = act ? csr_src[idx] : 0;
        float w = act ? csr_w[idx] : 0.f;
        float4 av = *(const float4*)(as_ + (size_t)s * 4);
        float l0 = av.x + adv.x + w * c0; l0 = l0 >= 0.f ? l0 : NEG_SLOPE * l0;
        float l1 = av.y + adv.y + w * c1; l1 = l1 >= 0.f ? l1 : NEG_SLOPE * l1;
        float l2 = av.z + adv.z + w * c2; l2 = l2 >= 0.f ? l2 : NEG_SLOPE * l2;
        float l3 = av.w + adv.w + w * c3; l3 = l3 >= 0.f ? l3 : NEG_SLOPE * l3;
        float lm = fmaxf(fmaxf(l0, l1), fmaxf(l2, l3));
        if (!act) lm = -INFINITY;
        for (int o = 32; o; o >>= 1) lm = fmaxf(lm, __shfl_xor(lm, o));
        float nm = fmaxf(m, lm);
        float sc = __expf(m - nm);
        m = nm;
        dn *= sc;
        acc0 *= sc; acc1 *= sc; acc2 *= sc; acc3 *= sc;
        acc4 *= sc; acc5 *= sc; acc6 *= sc; acc7 *= sc;
        float p0 = act ? __expf(l0 - m) : 0.f;
        float p1 = act ? __expf(l1 - m) : 0.f;
        float p2 = act ? __expf(l2 - m) : 0.f;
        float p3 = act ? __expf(l3 - m) : 0.f;
        float4 pv = { p0, p1, p2, p3 };
        *(float4*)&p_lds[wid][lane << 2] = pv;
        s_lds[wid][lane] = s;
        int cnt = end - base; if (cnt > 64) cnt = 64;
        int k = 0;
        for (; k + 8 <= cnt; k += 8) {
            int i0 = k + e0, i1 = k + 2 + e0, i2 = k + 4 + e0, i3 = k + 6 + e0;
            int s0 = s_lds[wid][i0], s1 = s_lds[wid][i1], s2 = s_lds[wid][i2], s3 = s_lds[wid][i3];
            uint4 u0 = *(const uint4*)(xbase + (size_t)s0 * 256);
            uint4 u1 = *(const uint4*)(xbase + (size_t)s1 * 256);
            uint4 u2 = *(const uint4*)(xbase + (size_t)s2 * 256);
            uint4 u3 = *(const uint4*)(xbase + (size_t)s3 * 256);
            float q0 = p_lds[wid][(i0 << 2) + hq2];
            float q1 = p_lds[wid][(i1 << 2) + hq2];
            float q2 = p_lds[wid][(i2 << 2) + hq2];
            float q3 = p_lds[wid][(i3 << 2) + hq2];
            dn += q0 + q1 + q2 + q3;
            ACC8(u0, q0); ACC8(u1, q1); ACC8(u2, q2); ACC8(u3, q3);
        }
        for (; k < cnt; k += 2) {
            int i = k + e0;
            bool v = i < cnt;
            int si = s_lds[wid][v ? i : 0];
            float qi = v ? p_lds[wid][(i << 2) + hq2] : 0.f;
            uint4 u = *(const uint4*)(xbase + (size_t)si * 256);
            dn += qi;
            ACC8(u, qi);
        }
    }
    acc0 += __shfl_xor(acc0, 32); acc1 += __shfl_xor(acc1, 32);
    acc2 += __shfl_xor(acc2, 32); acc3 += __shfl_xor(acc3, 32);
    acc4 += __shfl_xor(acc4, 32); acc5 += __shfl_xor(acc5, 32);
    acc6 += __shfl_xor(acc6, 32); acc7 += __shfl_xor(acc7, 32);
    dn += __shfl_xor(dn, 32);
    float inv = 1.f / dn;
    int cb8 = colb << 3;
    float4 bA = *(const float4*)(bias + cb8);
    float4 bB = *(const float4*)(bias + cb8 + 4);
    float o0 = acc0 * inv + bA.x, o1 = acc1 * inv + bA.y, o2 = acc2 * inv + bA.z, o3 = acc3 * inv + bA.w;
    float o4 = acc4 * inv + bB.x, o5 = acc5 * inv + bB.y, o6 = acc6 * inv + bB.z, o7 = acc7 * inv + bB.w;
    float part = ((o0 + o1) + (o2 + o3)) + ((o4 + o5) + (o6 + o7));
    for (int o = 16; o; o >>= 1) part += __shfl_xor(part, o);
    float mu = part * (1.f / 256.f);
    float d0 = o0 - mu, d1 = o1 - mu, d2 = o2 - mu, d3 = o3 - mu;
    float d4 = o4 - mu, d5 = o5 - mu, d6 = o6 - mu, d7 = o7 - mu;
    float vpart = ((d0 * d0 + d1 * d1) + (d2 * d2 + d3 * d3)) + ((d4 * d4 + d5 * d5) + (d6 * d6 + d7 * d7));
    for (int o = 16; o; o >>= 1) vpart += __shfl_xor(vpart, o);
    float rstd = rsqrtf(vpart * (1.f / 256.f) + LN_EPS);
    float4 gA = *(const float4*)(ln_g + cb8), gB = *(const float4*)(ln_g + cb8 + 4);
    float4 eA = *(const float4*)(ln_b + cb8), eB = *(const float4*)(ln_b + cb8 + 4);
    float y0 = d0 * rstd * gA.x + eA.x; y0 = y0 > 0.f ? y0 : __expf(y0) - 1.f;
    float y1 = d1 * rstd * gA.y + eA.y; y1 = y1 > 0.f ? y1 : __expf(y1) - 1.f;
    float y2 = d2 * rstd * gA.z + eA.z; y2 = y2 > 0.f ? y2 : __expf(y2) - 1.f;
    float y3 = d3 * rstd * gA.w + eA.w; y3 = y3 > 0.f ? y3 : __expf(y3) - 1.f;
    float y4 = d4 * rstd * gB.x + eB.x; y4 = y4 > 0.f ? y4 : __expf(y4) - 1.f;
    float y5 = d5 * rstd * gB.y + eB.y; y5 = y5 > 0.f ? y5 : __expf(y5) - 1.f;
    float y6 = d6 * rstd * gB.z + eB.z; y6 = y6 > 0.f ? y6 : __expf(y6) - 1.f;
    float y7 = d7 * rstd * gB.w + eB.w; y7 = y7 > 0.f ? y7 : __expf(y7) - 1.f;
    if (lane < 32) {
        uint4 ov;
        ov.x = ((unsigned int)f2bf(y1) << 16) | f2bf(y0);
        ov.y = ((unsigned int)f2bf(y3) << 16) | f2bf(y2);
        ov.z = ((unsigned int)f2bf(y5) << 16) | f2bf(y4);
        ov.w = ((unsigned int)f2bf(y7) << 16) | f2bf(y6);
        *(uint4*)(out16 + (size_t)n * HID + cb8) = ov;
    }
}

// ================= batch mean pool (bf16 input), 4-way unrolled =================
__device__ __forceinline__ int lower_bound_i(const int* a, int n, int key) {
    int lo = 0, hi = n;
    while (lo < hi) { int mid = (lo + hi) >> 1; if (a[mid] < key) lo = mid + 1; else hi = mid; }
    return lo;
}

__global__ __launch_bounds__(256) void pool_kernel(const unsigned short* __restrict__ h, const int* __restrict__ batch,
                                                   int N, float* __restrict__ out) {
    int b = blockIdx.x;
    int lo = lower_bound_i(batch, N, b);
    int hi = lower_bound_i(batch, N, b + 1);
    float a0 = 0.f, a1 = 0.f, a2 = 0.f, a3 = 0.f;
    int n = lo;
    for (; n + 4 <= hi; n += 4) {
        a0 += bf2f_u(h[(size_t)(n + 0) * HID + threadIdx.x]);
        a1 += bf2f_u(h[(size_t)(n + 1) * HID + threadIdx.x]);
        a2 += bf2f_u(h[(size_t)(n + 2) * HID + threadIdx.x]);
        a3 += bf2f_u(h[(size_t)(n + 3) * HID + threadIdx.x]);
    }
    for (; n < hi; n++) a0 += bf2f_u(h[(size_t)n * HID + threadIdx.x]);
    float acc = (a0 + a1) + (a2 + a3);
    out[(size_t)b * HID + threadIdx.x] = acc / fmaxf((float)(hi - lo), 1.f);
}

extern "C" void kernel_launch(void* const* d_in, const int* in_sizes, int n_in,
                              void* d_out, int out_size, void* d_ws, size_t ws_size,
                              hipStream_t stream) {
    const float* x    = (const float*)d_in[0];
    const int*   ei   = (const int*)d_in[1];
    const float* ew   = (const float*)d_in[2];
    const int*   batch= (const int*)d_in[3];
    const float* W1   = (const float*)d_in[4];
    const float* as1  = (const float*)d_in[5];
    const float* ad1  = (const float*)d_in[6];
    const float* ae1  = (const float*)d_in[7];
    const float* We1  = (const float*)d_in[8];
    const float* b1   = (const float*)d_in[9];
    const float* W2   = (const float*)d_in[10];
    const float* as2  = (const float*)d_in[11];
    const float* ad2  = (const float*)d_in[12];
    const float* ae2  = (const float*)d_in[13];
    const float* We2  = (const float*)d_in[14];
    const float* b2   = (const float*)d_in[15];
    const float* ln1g = (const float*)d_in[16];
    const float* ln1b = (const float*)d_in[17];
    const float* ln2g = (const float*)d_in[18];
    const float* ln2b = (const float*)d_in[19];

    int N = in_sizes[3];
    int E = in_sizes[2];
    int FIN = in_sizes[0] / N;
    int EN = E + N;
    int B = out_size / HID;
    float* outp = (float*)d_out;
    int NB = (N + 255) / 256;          // <= 256 required (N=50000 -> 196)
    int NH = (EN + 1023) / 1024;       // hist blocks
    int NSc = (EN + 1023) / 1024;      // scatter blocks

    char* ws = (char*)d_ws;
    size_t off = 0;
    auto alloc = [&](size_t bytes) { void* p = ws + off; off = (off + bytes + 255) & ~(size_t)255; return p; };
    float* sumw    = (float*)alloc(4);
    int*   deg     = (int*)  alloc((size_t)N * 4);           // zeroed region = [0, 256 + N*4)
    size_t zero_bytes = 256 + (size_t)N * 4;
    float* partials= (float*)alloc(256 * 4);
    int*   bsum    = (int*)  alloc(256 * 4);
    int*   offs    = (int*)  alloc((size_t)(N + 1) * 4);
    int*   cursor  = (int*)  alloc((size_t)N * 4);
    int*   csr_eid = (int*)  alloc((size_t)EN * 4);
    int*   csr_src = (int*)  alloc((size_t)EN * 4);
    float* csr_w   = (float*)alloc((size_t)EN * 4);
    float* asb     = (float*)alloc((size_t)N * 4 * 4);
    float* adb     = (float*)alloc((size_t)N * 4 * 4);
    float* cc      = (float*)alloc(64);
    unsigned short* w1_16 = (unsigned short*)alloc((size_t)HID * HID * 2);
    unsigned short* w2_16 = (unsigned short*)alloc((size_t)HID * HID * 2);
    unsigned short* x16   = (unsigned short*)alloc((size_t)N * HID * 2);  // x -> h1 -> h2 (reused)
    unsigned short* xp16  = (unsigned short*)alloc((size_t)N * HID * 2);
    (void)ws_size; (void)n_in;

    int MB = (N + 31) / 32;

    (void)hipMemsetAsync(d_ws, 0, zero_bytes, stream);
    k_pre<<<256 + NH + 512 + N, 256, 0, stream>>>(ew, E, ei, N, EN, NH, partials, deg,
                                                  W1, W2, w1_16, w2_16, FIN, x, x16, FIN);
    k_scanred_coeff<<<NB + 2, 256, 0, stream>>>(deg, N, NB, bsum, partials, sumw, We1, ae1, We2, ae2, cc, cc + 4);
    k_scan_apply<<<NB, 256, 0, stream>>>(deg, N, NB, bsum, offs, cursor);
    // scatter || layer-1 gemm (independent; scatter hides under gemm)
    k_scatter_gemm<<<NSc + MB, 256, 0, stream>>>(NSc, ei, E, EN, cursor, csr_eid,
                                                 x16, w1_16, N, as1, ad1, xp16, asb, adb);
    // deterministic order restore + payload gather (short serial kernel)
    k_sort_gather<<<(N + 3) / 4, 256, 0, stream>>>(offs, csr_eid, ei, ew, sumw, E, N, csr_src, csr_w);
    // layer 1 gat
    gat_kernel<<<(N + 3) / 4, 256, 0, stream>>>(xp16, offs, csr_src, csr_w, asb, adb, cc, b1, ln1g, ln1b, N, x16);
    // layer 2
    gemm_mfma<<<MB, 256, 0, stream>>>(x16, w2_16, N, as2, ad2, xp16, asb, adb);
    gat_kernel<<<(N + 3) / 4, 256, 0, stream>>>(xp16, offs, csr_src, csr_w, asb, adb, cc + 4, b2, ln2g, ln2b, N, x16);
    // pool
    pool_kernel<<<B, 256, 0, stream>>>(x16, batch, N, outp);
}

// Round 17
// 333.988 us; speedup vs baseline: 1.0707x; 1.0452x over previous
//
#include <hip/hip_runtime.h>
#include <math.h>

#define HID 256
#define NEG_SLOPE 0.2f
#define LN_EPS 1e-5f
#define MAXDEG 128

typedef __attribute__((ext_vector_type(4))) float f32x4;
typedef __attribute__((ext_vector_type(8))) short bf16x8;
typedef __attribute__((address_space(3))) unsigned char lds_b;
typedef const __attribute__((address_space(1))) unsigned char glob_b;

__device__ __forceinline__ float bf2f_lo(unsigned int u) {
    union { unsigned int i; float f; } c; c.i = u << 16; return c.f;
}
__device__ __forceinline__ float bf2f_hi(unsigned int u) {
    union { unsigned int i; float f; } c; c.i = u & 0xffff0000u; return c.f;
}
__device__ __forceinline__ float bf2f_u(unsigned short u) {
    union { unsigned int i; float f; } c; c.i = ((unsigned int)u) << 16; return c.f;
}
__device__ __forceinline__ unsigned short f2bf(float f) {
    union { float f; unsigned int i; } c; c.f = f;
    unsigned int i = c.i;
    return (unsigned short)((i + 0x7fffu + ((i >> 16) & 1u)) >> 16);
}

// ================= k_pre: bin-scatter (0..NH-1) + ew-sum + cvt_w + cvt_pad, one grid =================
// Bin scatter replaces BOTH hist and CSR scatter: final bin_cnt == deg. Half the atomics.
__global__ __launch_bounds__(256) void k_pre(const float* __restrict__ ew, int E,
                                             const int* __restrict__ ei, int N, int EN, int NH,
                                             float* __restrict__ partials, int* __restrict__ bin_cnt,
                                             int* __restrict__ bins, int* __restrict__ spill, int* __restrict__ spill_cnt,
                                             const float* __restrict__ W1, const float* __restrict__ W2,
                                             unsigned short* __restrict__ o1, unsigned short* __restrict__ o2, int K1,
                                             const float* __restrict__ x, unsigned short* __restrict__ x16, int FIN) {
    int t = threadIdx.x;
    int b = blockIdx.x;
    if (b < NH) {
        int i = b * 1024 + t;
#pragma unroll
        for (int c = 0; c < 4; c++) {
            int e = i + c * 256;
            if (e < EN) {
                int d = (e < E) ? ei[E + e] : (e - E);
                int pos = atomicAdd(&bin_cnt[d], 1);
                if (pos < MAXDEG) bins[(size_t)d * MAXDEG + pos] = e;
                else { int q = atomicAdd(spill_cnt, 1); spill[2 * q] = d; spill[2 * q + 1] = e; }
            }
        }
    } else if (b < NH + 256) {
        __shared__ float sdata[4];
        int sb = b - NH;
        float v = 0.f;
        for (int i = sb * 256 + t; i < E; i += 65536) v += ew[i];
        for (int o = 32; o; o >>= 1) v += __shfl_xor(v, o);
        if ((t & 63) == 0) sdata[t >> 6] = v;
        __syncthreads();
        if (t == 0) partials[sb] = sdata[0] + sdata[1] + sdata[2] + sdata[3];
    } else if (b < NH + 256 + 512) {
        int wb = b - NH - 256;
        const float* in = (wb < 256) ? W1 : W2;
        unsigned short* out = (wb < 256) ? o1 : o2;
        int K = (wb < 256) ? K1 : 256;
        int col = wb & 255;
        float v = (t < K) ? in[(size_t)col * K + t] : 0.f;
        int ks = t >> 5, j = (t >> 3) & 3, e = t & 7;
        out[ks * 8192 + j * 2048 + ((((col << 4) ^ (j << 4))) >> 1) + e] = f2bf(v);
    } else {
        int r = b - NH - 256 - 512;
        x16[(size_t)r * 256 + t] = (t < FIN) ? f2bf(x[(size_t)r * FIN + t]) : (unsigned short)0;
    }
}

// ================= merged: per-block degree sums + sumw finish + coeff =================
__global__ __launch_bounds__(256) void k_scanred_coeff(const int* __restrict__ deg, int N, int NB,
                                                       int* __restrict__ bsum,
                                                       const float* __restrict__ partials, float* __restrict__ sumw,
                                                       const float* __restrict__ We1, const float* __restrict__ ae1,
                                                       const float* __restrict__ We2, const float* __restrict__ ae2,
                                                       float* __restrict__ c1, float* __restrict__ c2) {
    int t = threadIdx.x;
    int b = blockIdx.x;
    if (b < NB) {
        __shared__ int sdata[4];
        int i = b * 256 + t;
        int v = (i < N) ? deg[i] : 0;
        for (int o = 32; o; o >>= 1) v += __shfl_xor(v, o);
        if ((t & 63) == 0) sdata[t >> 6] = v;
        __syncthreads();
        if (t == 0) bsum[b] = sdata[0] + sdata[1] + sdata[2] + sdata[3];
    } else if (b == NB) {
        __shared__ float sdata[4];
        float v = partials[t];
        for (int o = 32; o; o >>= 1) v += __shfl_xor(v, o);
        if ((t & 63) == 0) sdata[t >> 6] = v;
        __syncthreads();
        if (t == 0) *sumw = sdata[0] + sdata[1] + sdata[2] + sdata[3];
    } else {
        float v1 = We1[t] * ae1[t];
        float v2 = We2[t] * ae2[t];
        for (int o = 1; o < 64; o <<= 1) { v1 += __shfl_xor(v1, o); v2 += __shfl_xor(v2, o); }
        if ((t & 63) == 0) { c1[t >> 6] = v1; c2[t >> 6] = v2; }
    }
}

// ================= scan_apply with inline scan of block sums (offs only) =================
__global__ __launch_bounds__(256) void k_scan_apply(const int* __restrict__ deg, int N, int NB,
                                                    const int* __restrict__ bsum, int* __restrict__ offs) {
    __shared__ int sm[256];
    __shared__ int sb[256];
    int t = threadIdx.x;
    int i = blockIdx.x * 256 + t;
    int v = (i < N) ? deg[i] : 0;
    int vb = (t < NB) ? bsum[t] : 0;
    sm[t] = v;
    sb[t] = vb;
    __syncthreads();
    for (int o = 1; o < 256; o <<= 1) {
        int tv = (t >= o) ? sm[t - o] : 0;
        int tb = (t >= o) ? sb[t - o] : 0;
        __syncthreads();
        sm[t] += tv;
        sb[t] += tb;
        __syncthreads();
    }
    int myb = bsum[blockIdx.x];
    int boff = sb[blockIdx.x] - myb;
    if (i < N) {
        offs[i] = boff + sm[t] - v;
        if (i == N - 1) offs[N] = boff + sm[t];
    }
}

// ================= gemm device body =================
__device__ __forceinline__ void gemm_dev(int bid,
    const unsigned short* __restrict__ A16, const unsigned short* __restrict__ Bt16, int M,
    const float* __restrict__ asf, const float* __restrict__ adf,
    unsigned short* __restrict__ C16, float* __restrict__ as_out, float* __restrict__ ad_out)
{
    __shared__ __align__(16) unsigned short Bsl[4 * 256 * 8]; // 16 KB
    int t = threadIdx.x;
    int lane = t & 63, w = t >> 6;
    int row0 = bid << 5;
    int kg = lane >> 4, fr = lane & 15;

    int ar0 = row0 + fr;      if (ar0 >= M) ar0 = 0;
    int ar1 = row0 + 16 + fr; if (ar1 >= M) ar1 = 0;
    const unsigned short* ap0 = A16 + (size_t)ar0 * 256 + (kg << 3);
    const unsigned short* ap1 = A16 + (size_t)ar1 * 256 + (kg << 3);

    f32x4 acc[2][4];
#pragma unroll
    for (int i = 0; i < 2; i++)
#pragma unroll
        for (int j = 0; j < 4; j++) acc[i][j] = (f32x4){0.f, 0.f, 0.f, 0.f};

    for (int ks = 0; ks < 8; ks++) {
#pragma unroll
        for (int j = 0; j < 4; j++) {
            __builtin_amdgcn_global_load_lds(
                (glob_b*)(Bt16 + (size_t)ks * 8192 + j * 2048 + t * 8),
                (lds_b*)((char*)Bsl + j * 4096 + t * 16),
                16, 0, 0);
        }
        bf16x8 a0 = *(const bf16x8*)(ap0 + (ks << 5));
        bf16x8 a1 = *(const bf16x8*)(ap1 + (ks << 5));
        __syncthreads();
#pragma unroll
        for (int nf = 0; nf < 4; nf++) {
            int col = (w << 6) + (nf << 4) + fr;
            bf16x8 bv = *(const bf16x8*)((const char*)Bsl + (kg << 12) + (((col << 4)) ^ (kg << 4)));
            acc[0][nf] = __builtin_amdgcn_mfma_f32_16x16x32_bf16(a0, bv, acc[0][nf], 0, 0, 0);
            acc[1][nf] = __builtin_amdgcn_mfma_f32_16x16x32_bf16(a1, bv, acc[1][nf], 0, 0, 0);
        }
        __syncthreads();
    }

#pragma unroll
    for (int mf = 0; mf < 2; mf++)
#pragma unroll
        for (int j = 0; j < 4; j++) {
            int gr = row0 + mf * 16 + kg * 4 + j;
            if (gr < M) {
#pragma unroll
                for (int nf = 0; nf < 4; nf++)
                    C16[(size_t)gr * 256 + (w << 6) + (nf << 4) + fr] = f2bf(acc[mf][nf][j]);
            }
        }
    float asv[4], adv[4];
#pragma unroll
    for (int nf = 0; nf < 4; nf++) {
        int col = (w << 6) + (nf << 4) + fr;
        asv[nf] = asf[col]; adv[nf] = adf[col];
    }
#pragma unroll
    for (int mf = 0; mf < 2; mf++)
#pragma unroll
        for (int j = 0; j < 4; j++) {
            float ps = acc[mf][0][j] * asv[0] + acc[mf][1][j] * asv[1] + acc[mf][2][j] * asv[2] + acc[mf][3][j] * asv[3];
            float pd = acc[mf][0][j] * adv[0] + acc[mf][1][j] * adv[1] + acc[mf][2][j] * adv[2] + acc[mf][3][j] * adv[3];
#pragma unroll
            for (int o = 1; o < 16; o <<= 1) { ps += __shfl_xor(ps, o); pd += __shfl_xor(pd, o); }
            if (fr == 0) {
                int gr = row0 + mf * 16 + kg * 4 + j;
                if (gr < M) {
                    as_out[gr * 4 + w] = ps;
                    ad_out[gr * 4 + w] = pd;
                }
            }
        }
}

// ================= compact+sort+gather from bins (atomic-free) =================
__device__ __forceinline__ void compact_dev(int bid, const int* __restrict__ offs,
                                            const int* __restrict__ bins,
                                            const int* __restrict__ spill, const int* __restrict__ spill_cnt,
                                            const int* __restrict__ ei, const float* __restrict__ ew,
                                            const float* __restrict__ sumw, int E, int N,
                                            int* __restrict__ csr_src, float* __restrict__ csr_w) {
    int lane = threadIdx.x & 63;
    int n = (bid << 2) + (threadIdx.x >> 6);
    if (n >= N) return;
    int s0 = offs[n];
    int d = offs[n + 1] - s0;
    if (d <= 0) return;
    if (d <= 64) {
        int key = (lane < d) ? bins[(size_t)n * MAXDEG + lane] : 0x7fffffff;
        int rank = 0;
        for (int j = 0; j < d; j++) {
            int kj = __shfl(key, j);
            rank += (kj < key) ? 1 : 0;
        }
        if (lane < d) {
            int s; float wv;
            if (key < E) { s = ei[key]; wv = ew[key]; }
            else         { s = key - E; wv = *sumw / (float)E; }
            csr_src[s0 + rank] = s;
            csr_w[s0 + rank] = wv;
        }
    } else {
        // cold path (P~0): collect bin + spill entries, sort by eid, then gather payloads
        if (lane == 0) {
            int m = (d < MAXDEG) ? d : MAXDEG;
            for (int i = 0; i < m; i++) csr_src[s0 + i] = bins[(size_t)n * MAXDEG + i];
            int cnt = m;
            int st = *spill_cnt;
            for (int k = 0; k < st; k++)
                if (spill[2 * k] == n) csr_src[s0 + cnt++] = spill[2 * k + 1];
            for (int i = s0 + 1; i < s0 + d; i++) {
                int ke = csr_src[i];
                int j = i - 1;
                while (j >= s0 && csr_src[j] > ke) { csr_src[j + 1] = csr_src[j]; j--; }
                csr_src[j + 1] = ke;
            }
        }
        __threadfence();
        __builtin_amdgcn_wave_barrier();
        for (int i = lane; i < d; i += 64) {
            int e = csr_src[s0 + i];
            int s; float wv;
            if (e < E) { s = ei[e]; wv = ew[e]; }
            else       { s = e - E; wv = *sumw / (float)E; }
            csr_src[s0 + i] = s;
            csr_w[s0 + i] = wv;
        }
    }
}

// ================= merged: gemm layer-1 (blocks [0,MB)) + compact/sort/gather =================
__global__ __launch_bounds__(256) void k_gemm_sort(int MB,
    const unsigned short* __restrict__ A16, const unsigned short* __restrict__ Bt16, int M,
    const float* __restrict__ asf, const float* __restrict__ adf,
    unsigned short* __restrict__ C16, float* __restrict__ as_out, float* __restrict__ ad_out,
    const int* __restrict__ offs, const int* __restrict__ bins,
    const int* __restrict__ spill, const int* __restrict__ spill_cnt,
    const int* __restrict__ ei, const float* __restrict__ ew,
    const float* __restrict__ sumw, int E,
    int* __restrict__ csr_src, float* __restrict__ csr_w) {
    if ((int)blockIdx.x < MB)
        gemm_dev(blockIdx.x, A16, Bt16, M, asf, adf, C16, as_out, ad_out);
    else
        compact_dev(blockIdx.x - MB, offs, bins, spill, spill_cnt, ei, ew, sumw, E, M, csr_src, csr_w);
}

// ================= standalone gemm (layer 2) =================
__global__ __launch_bounds__(256) void gemm_mfma(
    const unsigned short* __restrict__ A16, const unsigned short* __restrict__ Bt16, int M,
    const float* __restrict__ asf, const float* __restrict__ adf,
    unsigned short* __restrict__ C16, float* __restrict__ as_out, float* __restrict__ ad_out) {
    gemm_dev(blockIdx.x, A16, Bt16, M, asf, adf, C16, as_out, ad_out);
}

// ================= fused GAT + bias + LN + ELU -> bf16 out =================
#define ACC8(u, q) do { \
    acc0 += (q) * bf2f_lo((u).x); acc1 += (q) * bf2f_hi((u).x); \
    acc2 += (q) * bf2f_lo((u).y); acc3 += (q) * bf2f_hi((u).y); \
    acc4 += (q) * bf2f_lo((u).z); acc5 += (q) * bf2f_hi((u).z); \
    acc6 += (q) * bf2f_lo((u).w); acc7 += (q) * bf2f_hi((u).w); } while (0)

__global__ __launch_bounds__(256) void gat_kernel(
    const unsigned short* __restrict__ xp16, const int* __restrict__ offs,
    const int* __restrict__ csr_src, const float* __restrict__ csr_w,
    const float* __restrict__ as_, const float* __restrict__ ad_,
    const float* __restrict__ cvec, const float* __restrict__ bias,
    const float* __restrict__ ln_g, const float* __restrict__ ln_b,
    int N, unsigned short* __restrict__ out16) {
    __shared__ float p_lds[4][256];
    __shared__ int   s_lds[4][64];
    int lane = threadIdx.x & 63;
    int wid = threadIdx.x >> 6;
    int n = (blockIdx.x << 2) + wid;
    if (n >= N) return;
    int start = offs[n], end = offs[n + 1];
    int e0 = lane >> 5;
    int colb = lane & 31;
    int hq2 = colb >> 3;
    const unsigned short* xbase = xp16 + (size_t)colb * 8;
    float4 adv = *(const float4*)(ad_ + (size_t)n * 4);
    float c0 = cvec[0], c1 = cvec[1], c2 = cvec[2], c3 = cvec[3];
    float m = -INFINITY, dn = 0.f;
    float acc0 = 0, acc1 = 0, acc2 = 0, acc3 = 0, acc4 = 0, acc5 = 0, acc6 = 0, acc7 = 0;

    for (int base = start; base < end; base += 64) {
        int idx = base + lane;
        bool act = idx < end;
        int s = act ? csr_src[idx] : 0;
        float w = act ? csr_w[idx] : 0.f;
        float4 av = *(const float4*)(as_ + (size_t)s * 4);
        float l0 = av.x + adv.x + w * c0; l0 = l0 >= 0.f ? l0 : NEG_SLOPE * l0;
        float l1 = av.y + adv.y + w * c1; l1 = l1 >= 0.f ? l1 : NEG_SLOPE * l1;
        float l2 = av.z + adv.z + w * c2; l2 = l2 >= 0.f ? l2 : NEG_SLOPE * l2;
        float l3 = av.w + adv.w + w * c3; l3 = l3 >= 0.f ? l3 : NEG_SLOPE * l3;
        float lm = fmaxf(fmaxf(l0, l1), fmaxf(l2, l3));
        if (!act) lm = -INFINITY;
        for (int o = 32; o; o >>= 1) lm = fmaxf(lm, __shfl_xor(lm, o));
        float nm = fmaxf(m, lm);
        float sc = __expf(m - nm);
        m = nm;
        dn *= sc;
        acc0 *= sc; acc1 *= sc; acc2 *= sc; acc3 *= sc;
        acc4 *= sc; acc5 *= sc; acc6 *= sc; acc7 *= sc;
        float p0 = act ? __expf(l0 - m) : 0.f;
        float p1 = act ? __expf(l1 - m) : 0.f;
        float p2 = act ? __expf(l2 - m) : 0.f;
        float p3 = act ? __expf(l3 - m) : 0.f;
        float4 pv = { p0, p1, p2, p3 };
        *(float4*)&p_lds[wid][lane << 2] = pv;
        s_lds[wid][lane] = s;
        int cnt = end - base; if (cnt > 64) cnt = 64;
        int k = 0;
        for (; k + 8 <= cnt; k += 8) {
            int i0 = k + e0, i1 = k + 2 + e0, i2 = k + 4 + e0, i3 = k + 6 + e0;
            int s0 = s_lds[wid][i0], s1 = s_lds[wid][i1], s2 = s_lds[wid][i2], s3 = s_lds[wid][i3];
            uint4 u0 = *(const uint4*)(xbase + (size_t)s0 * 256);
            uint4 u1 = *(const uint4*)(xbase + (size_t)s1 * 256);
            uint4 u2 = *(const uint4*)(xbase + (size_t)s2 * 256);
            uint4 u3 = *(const uint4*)(xbase + (size_t)s3 * 256);
            float q0 = p_lds[wid][(i0 << 2) + hq2];
            float q1 = p_lds[wid][(i1 << 2) + hq2];
            float q2 = p_lds[wid][(i2 << 2) + hq2];
            float q3 = p_lds[wid][(i3 << 2) + hq2];
            dn += q0 + q1 + q2 + q3;
            ACC8(u0, q0); ACC8(u1, q1); ACC8(u2, q2); ACC8(u3, q3);
        }
        for (; k < cnt; k += 2) {
            int i = k + e0;
            bool v = i < cnt;
            int si = s_lds[wid][v ? i : 0];
            float qi = v ? p_lds[wid][(i << 2) + hq2] : 0.f;
            uint4 u = *(const uint4*)(xbase + (size_t)si * 256);
            dn += qi;
            ACC8(u, qi);
        }
    }
    acc0 += __shfl_xor(acc0, 32); acc1 += __shfl_xor(acc1, 32);
    acc2 += __shfl_xor(acc2, 32); acc3 += __shfl_xor(acc3, 32);
    acc4 += __shfl_xor(acc4, 32); acc5 += __shfl_xor(acc5, 32);
    acc6 += __shfl_xor(acc6, 32); acc7 += __shfl_xor(acc7, 32);
    dn += __shfl_xor(dn, 32);
    float inv = 1.f / dn;
    int cb8 = colb << 3;
    float4 bA = *(const float4*)(bias + cb8);
    float4 bB = *(const float4*)(bias + cb8 + 4);
    float o0 = acc0 * inv + bA.x, o1 = acc1 * inv + bA.y, o2 = acc2 * inv + bA.z, o3 = acc3 * inv + bA.w;
    float o4 = acc4 * inv + bB.x, o5 = acc5 * inv + bB.y, o6 = acc6 * inv + bB.z, o7 = acc7 * inv + bB.w;
    float part = ((o0 + o1) + (o2 + o3)) + ((o4 + o5) + (o6 + o7));
    for (int o = 16; o; o >>= 1) part += __shfl_xor(part, o);
    float mu = part * (1.f / 256.f);
    float d0 = o0 - mu, d1 = o1 - mu, d2 = o2 - mu, d3 = o3 - mu;
    float d4 = o4 - mu, d5 = o5 - mu, d6 = o6 - mu, d7 = o7 - mu;
    float vpart = ((d0 * d0 + d1 * d1) + (d2 * d2 + d3 * d3)) + ((d4 * d4 + d5 * d5) + (d6 * d6 + d7 * d7));
    for (int o = 16; o; o >>= 1) vpart += __shfl_xor(vpart, o);
    float rstd = rsqrtf(vpart * (1.f / 256.f) + LN_EPS);
    float4 gA = *(const float4*)(ln_g + cb8), gB = *(const float4*)(ln_g + cb8 + 4);
    float4 eA = *(const float4*)(ln_b + cb8), eB = *(const float4*)(ln_b + cb8 + 4);
    float y0 = d0 * rstd * gA.x + eA.x; y0 = y0 > 0.f ? y0 : __expf(y0) - 1.f;
    float y1 = d1 * rstd * gA.y + eA.y; y1 = y1 > 0.f ? y1 : __expf(y1) - 1.f;
    float y2 = d2 * rstd * gA.z + eA.z; y2 = y2 > 0.f ? y2 : __expf(y2) - 1.f;
    float y3 = d3 * rstd * gA.w + eA.w; y3 = y3 > 0.f ? y3 : __expf(y3) - 1.f;
    float y4 = d4 * rstd * gB.x + eB.x; y4 = y4 > 0.f ? y4 : __expf(y4) - 1.f;
    float y5 = d5 * rstd * gB.y + eB.y; y5 = y5 > 0.f ? y5 : __expf(y5) - 1.f;
    float y6 = d6 * rstd * gB.z + eB.z; y6 = y6 > 0.f ? y6 : __expf(y6) - 1.f;
    float y7 = d7 * rstd * gB.w + eB.w; y7 = y7 > 0.f ? y7 : __expf(y7) - 1.f;
    if (lane < 32) {
        uint4 ov;
        ov.x = ((unsigned int)f2bf(y1) << 16) | f2bf(y0);
        ov.y = ((unsigned int)f2bf(y3) << 16) | f2bf(y2);
        ov.z = ((unsigned int)f2bf(y5) << 16) | f2bf(y4);
        ov.w = ((unsigned int)f2bf(y7) << 16) | f2bf(y6);
        *(uint4*)(out16 + (size_t)n * HID + cb8) = ov;
    }
}

// ================= batch mean pool (bf16 input), 4-way unrolled =================
__device__ __forceinline__ int lower_bound_i(const int* a, int n, int key) {
    int lo = 0, hi = n;
    while (lo < hi) { int mid = (lo + hi) >> 1; if (a[mid] < key) lo = mid + 1; else hi = mid; }
    return lo;
}

__global__ __launch_bounds__(256) void pool_kernel(const unsigned short* __restrict__ h, const int* __restrict__ batch,
                                                   int N, float* __restrict__ out) {
    int b = blockIdx.x;
    int lo = lower_bound_i(batch, N, b);
    int hi = lower_bound_i(batch, N, b + 1);
    float a0 = 0.f, a1 = 0.f, a2 = 0.f, a3 = 0.f;
    int n = lo;
    for (; n + 4 <= hi; n += 4) {
        a0 += bf2f_u(h[(size_t)(n + 0) * HID + threadIdx.x]);
        a1 += bf2f_u(h[(size_t)(n + 1) * HID + threadIdx.x]);
        a2 += bf2f_u(h[(size_t)(n + 2) * HID + threadIdx.x]);
        a3 += bf2f_u(h[(size_t)(n + 3) * HID + threadIdx.x]);
    }
    for (; n < hi; n++) a0 += bf2f_u(h[(size_t)n * HID + threadIdx.x]);
    float acc = (a0 + a1) + (a2 + a3);
    out[(size_t)b * HID + threadIdx.x] = acc / fmaxf((float)(hi - lo), 1.f);
}

extern "C" void kernel_launch(void* const* d_in, const int* in_sizes, int n_in,
                              void* d_out, int out_size, void* d_ws, size_t ws_size,
                              hipStream_t stream) {
    const float* x    = (const float*)d_in[0];
    const int*   ei   = (const int*)d_in[1];
    const float* ew   = (const float*)d_in[2];
    const int*   batch= (const int*)d_in[3];
    const float* W1   = (const float*)d_in[4];
    const float* as1  = (const float*)d_in[5];
    const float* ad1  = (const float*)d_in[6];
    const float* ae1  = (const float*)d_in[7];
    const float* We1  = (const float*)d_in[8];
    const float* b1   = (const float*)d_in[9];
    const float* W2   = (const float*)d_in[10];
    const float* as2  = (const float*)d_in[11];
    const float* ad2  = (const float*)d_in[12];
    const float* ae2  = (const float*)d_in[13];
    const float* We2  = (const float*)d_in[14];
    const float* b2   = (const float*)d_in[15];
    const float* ln1g = (const float*)d_in[16];
    const float* ln1b = (const float*)d_in[17];
    const float* ln2g = (const float*)d_in[18];
    const float* ln2b = (const float*)d_in[19];

    int N = in_sizes[3];
    int E = in_sizes[2];
    int FIN = in_sizes[0] / N;
    int EN = E + N;
    int B = out_size / HID;
    float* outp = (float*)d_out;
    int NB = (N + 255) / 256;          // <= 256 required (N=50000 -> 196)
    int NH = (EN + 1023) / 1024;       // bin-scatter blocks

    char* ws = (char*)d_ws;
    size_t off = 0;
    auto alloc = [&](size_t bytes) { void* p = ws + off; off = (off + bytes + 255) & ~(size_t)255; return p; };
    float* sumw      = (float*)alloc(4);                      // zeroed
    int*   spill_cnt = (int*)  alloc(4);                      // zeroed
    int*   bin_cnt   = (int*)  alloc((size_t)N * 4);          // zeroed; == deg after k_pre
    size_t zero_bytes = 512 + (size_t)N * 4;
    float* partials= (float*)alloc(256 * 4);
    int*   bsum    = (int*)  alloc(256 * 4);
    int*   offs    = (int*)  alloc((size_t)(N + 1) * 4);
    int*   bins    = (int*)  alloc((size_t)N * MAXDEG * 4);
    int*   spill   = (int*)  alloc((size_t)EN * 2 * 4);
    int*   csr_src = (int*)  alloc((size_t)EN * 4);
    float* csr_w   = (float*)alloc((size_t)EN * 4);
    float* asb     = (float*)alloc((size_t)N * 4 * 4);
    float* adb     = (float*)alloc((size_t)N * 4 * 4);
    float* cc      = (float*)alloc(64);
    unsigned short* w1_16 = (unsigned short*)alloc((size_t)HID * HID * 2);
    unsigned short* w2_16 = (unsigned short*)alloc((size_t)HID * HID * 2);
    unsigned short* x16   = (unsigned short*)alloc((size_t)N * HID * 2);  // x -> h1 -> h2 (reused)
    unsigned short* xp16  = (unsigned short*)alloc((size_t)N * HID * 2);
    (void)ws_size; (void)n_in;

    int MB = (N + 31) / 32;
    int NC = (N + 3) / 4;              // compact blocks

    (void)hipMemsetAsync(d_ws, 0, zero_bytes, stream);
    k_pre<<<NH + 256 + 512 + N, 256, 0, stream>>>(ew, E, ei, N, EN, NH, partials, bin_cnt,
                                                  bins, spill, spill_cnt,
                                                  W1, W2, w1_16, w2_16, FIN, x, x16, FIN);
    k_scanred_coeff<<<NB + 2, 256, 0, stream>>>(bin_cnt, N, NB, bsum, partials, sumw, We1, ae1, We2, ae2, cc, cc + 4);
    k_scan_apply<<<NB, 256, 0, stream>>>(bin_cnt, N, NB, bsum, offs);
    // layer-1 gemm || atomic-free compact+sort+gather
    k_gemm_sort<<<MB + NC, 256, 0, stream>>>(MB, x16, w1_16, N, as1, ad1, xp16, asb, adb,
                                             offs, bins, spill, spill_cnt, ei, ew, sumw, E, csr_src, csr_w);
    // layer 1 gat
    gat_kernel<<<NC, 256, 0, stream>>>(xp16, offs, csr_src, csr_w, asb, adb, cc, b1, ln1g, ln1b, N, x16);
    // layer 2
    gemm_mfma<<<MB, 256, 0, stream>>>(x16, w2_16, N, as2, ad2, xp16, asb, adb);
    gat_kernel<<<NC, 256, 0, stream>>>(xp16, offs, csr_src, csr_w, asb, adb, cc + 4, b2, ln2g, ln2b, N, x16);
    // pool
    pool_kernel<<<B, 256, 0, stream>>>(x16, batch, N, outp);
}

// Round 18
// 303.921 us; speedup vs baseline: 1.1767x; 1.0989x over previous
//
#include <hip/hip_runtime.h>
#include <math.h>

#define HID 256
#define NEG_SLOPE 0.2f
#define LN_EPS 1e-5f
#define BINCAP 127   // bins row: [cnt | 127 slots]

typedef __attribute__((ext_vector_type(4))) float f32x4;
typedef __attribute__((ext_vector_type(8))) short bf16x8;
typedef __attribute__((address_space(3))) unsigned char lds_b;
typedef const __attribute__((address_space(1))) unsigned char glob_b;

__device__ __forceinline__ float bf2f_lo(unsigned int u) {
    union { unsigned int i; float f; } c; c.i = u << 16; return c.f;
}
__device__ __forceinline__ float bf2f_hi(unsigned int u) {
    union { unsigned int i; float f; } c; c.i = u & 0xffff0000u; return c.f;
}
__device__ __forceinline__ float bf2f_u(unsigned short u) {
    union { unsigned int i; float f; } c; c.i = ((unsigned int)u) << 16; return c.f;
}
__device__ __forceinline__ unsigned short f2bf(float f) {
    union { float f; unsigned int i; } c; c.f = f;
    unsigned int i = c.i;
    return (unsigned short)((i + 0x7fffu + ((i >> 16) & 1u)) >> 16);
}

// ================= k_pre: bin-scatter (counter inside bin row) + ew-sum + cvt_w + cvt_pad =================
__global__ __launch_bounds__(256) void k_pre(const float* __restrict__ ew, int E,
                                             const int* __restrict__ ei, int N, int EN, int NH,
                                             float* __restrict__ partials,
                                             int* __restrict__ bins, int* __restrict__ spill, int* __restrict__ spill_cnt,
                                             const float* __restrict__ W1, const float* __restrict__ W2,
                                             unsigned short* __restrict__ o1, unsigned short* __restrict__ o2, int K1,
                                             const float* __restrict__ x, unsigned short* __restrict__ x16, int FIN) {
    int t = threadIdx.x;
    int b = blockIdx.x;
    if (b < NH) {
        int i = b * 1024 + t;
#pragma unroll
        for (int c = 0; c < 4; c++) {
            int e = i + c * 256;
            if (e < EN) {
                int d = (e < E) ? ei[E + e] : (e - E);
                int* row = bins + (size_t)d * 128;
                int pos = atomicAdd(row, 1);
                if (pos < BINCAP) row[1 + pos] = e;   // ~87% same 64B line as the atomic
                else { int q = atomicAdd(spill_cnt, 1); spill[2 * q] = d; spill[2 * q + 1] = e; }
            }
        }
    } else if (b < NH + 256) {
        __shared__ float sdata[4];
        int sb = b - NH;
        float v = 0.f;
        for (int i = sb * 256 + t; i < E; i += 65536) v += ew[i];
        for (int o = 32; o; o >>= 1) v += __shfl_xor(v, o);
        if ((t & 63) == 0) sdata[t >> 6] = v;
        __syncthreads();
        if (t == 0) partials[sb] = sdata[0] + sdata[1] + sdata[2] + sdata[3];
    } else if (b < NH + 256 + 512) {
        int wb = b - NH - 256;
        const float* in = (wb < 256) ? W1 : W2;
        unsigned short* out = (wb < 256) ? o1 : o2;
        int K = (wb < 256) ? K1 : 256;
        int col = wb & 255;
        float v = (t < K) ? in[(size_t)col * K + t] : 0.f;
        int ks = t >> 5, j = (t >> 3) & 3, e = t & 7;
        out[ks * 8192 + j * 2048 + ((((col << 4) ^ (j << 4))) >> 1) + e] = f2bf(v);
    } else {
        int r = b - NH - 256 - 512;
        x16[(size_t)r * 256 + t] = (t < FIN) ? f2bf(x[(size_t)r * FIN + t]) : (unsigned short)0;
    }
}

// ================= merged: per-block degree sums (+ dense deg copy) + sumw finish + coeff =================
__global__ __launch_bounds__(256) void k_scanred_coeff(const int* __restrict__ bins, int N, int NB,
                                                       int* __restrict__ deg_dense, int* __restrict__ bsum,
                                                       const float* __restrict__ partials, float* __restrict__ sumw,
                                                       const float* __restrict__ We1, const float* __restrict__ ae1,
                                                       const float* __restrict__ We2, const float* __restrict__ ae2,
                                                       float* __restrict__ c1, float* __restrict__ c2) {
    int t = threadIdx.x;
    int b = blockIdx.x;
    if (b < NB) {
        __shared__ int sdata[4];
        int i = b * 256 + t;
        int v = (i < N) ? bins[(size_t)i * 128] : 0;
        if (i < N) deg_dense[i] = v;
        for (int o = 32; o; o >>= 1) v += __shfl_xor(v, o);
        if ((t & 63) == 0) sdata[t >> 6] = v;
        __syncthreads();
        if (t == 0) bsum[b] = sdata[0] + sdata[1] + sdata[2] + sdata[3];
    } else if (b == NB) {
        __shared__ float sdata[4];
        float v = partials[t];
        for (int o = 32; o; o >>= 1) v += __shfl_xor(v, o);
        if ((t & 63) == 0) sdata[t >> 6] = v;
        __syncthreads();
        if (t == 0) *sumw = sdata[0] + sdata[1] + sdata[2] + sdata[3];
    } else {
        float v1 = We1[t] * ae1[t];
        float v2 = We2[t] * ae2[t];
        for (int o = 1; o < 64; o <<= 1) { v1 += __shfl_xor(v1, o); v2 += __shfl_xor(v2, o); }
        if ((t & 63) == 0) { c1[t >> 6] = v1; c2[t >> 6] = v2; }
    }
}

// ================= scan_apply with inline scan of block sums (offs only) =================
__global__ __launch_bounds__(256) void k_scan_apply(const int* __restrict__ deg, int N, int NB,
                                                    const int* __restrict__ bsum, int* __restrict__ offs) {
    __shared__ int sm[256];
    __shared__ int sb[256];
    int t = threadIdx.x;
    int i = blockIdx.x * 256 + t;
    int v = (i < N) ? deg[i] : 0;
    int vb = (t < NB) ? bsum[t] : 0;
    sm[t] = v;
    sb[t] = vb;
    __syncthreads();
    for (int o = 1; o < 256; o <<= 1) {
        int tv = (t >= o) ? sm[t - o] : 0;
        int tb = (t >= o) ? sb[t - o] : 0;
        __syncthreads();
        sm[t] += tv;
        sb[t] += tb;
        __syncthreads();
    }
    int myb = bsum[blockIdx.x];
    int boff = sb[blockIdx.x] - myb;
    if (i < N) {
        offs[i] = boff + sm[t] - v;
        if (i == N - 1) offs[N] = boff + sm[t];
    }
}

// ================= gemm device body =================
__device__ __forceinline__ void gemm_dev(int bid,
    const unsigned short* __restrict__ A16, const unsigned short* __restrict__ Bt16, int M,
    const float* __restrict__ asf, const float* __restrict__ adf,
    unsigned short* __restrict__ C16, float* __restrict__ as_out, float* __restrict__ ad_out)
{
    __shared__ __align__(16) unsigned short Bsl[4 * 256 * 8]; // 16 KB
    int t = threadIdx.x;
    int lane = t & 63, w = t >> 6;
    int row0 = bid << 5;
    int kg = lane >> 4, fr = lane & 15;

    int ar0 = row0 + fr;      if (ar0 >= M) ar0 = 0;
    int ar1 = row0 + 16 + fr; if (ar1 >= M) ar1 = 0;
    const unsigned short* ap0 = A16 + (size_t)ar0 * 256 + (kg << 3);
    const unsigned short* ap1 = A16 + (size_t)ar1 * 256 + (kg << 3);

    f32x4 acc[2][4];
#pragma unroll
    for (int i = 0; i < 2; i++)
#pragma unroll
        for (int j = 0; j < 4; j++) acc[i][j] = (f32x4){0.f, 0.f, 0.f, 0.f};

    for (int ks = 0; ks < 8; ks++) {
#pragma unroll
        for (int j = 0; j < 4; j++) {
            __builtin_amdgcn_global_load_lds(
                (glob_b*)(Bt16 + (size_t)ks * 8192 + j * 2048 + t * 8),
                (lds_b*)((char*)Bsl + j * 4096 + t * 16),
                16, 0, 0);
        }
        bf16x8 a0 = *(const bf16x8*)(ap0 + (ks << 5));
        bf16x8 a1 = *(const bf16x8*)(ap1 + (ks << 5));
        __syncthreads();
#pragma unroll
        for (int nf = 0; nf < 4; nf++) {
            int col = (w << 6) + (nf << 4) + fr;
            bf16x8 bv = *(const bf16x8*)((const char*)Bsl + (kg << 12) + (((col << 4)) ^ (kg << 4)));
            acc[0][nf] = __builtin_amdgcn_mfma_f32_16x16x32_bf16(a0, bv, acc[0][nf], 0, 0, 0);
            acc[1][nf] = __builtin_amdgcn_mfma_f32_16x16x32_bf16(a1, bv, acc[1][nf], 0, 0, 0);
        }
        __syncthreads();
    }

#pragma unroll
    for (int mf = 0; mf < 2; mf++)
#pragma unroll
        for (int j = 0; j < 4; j++) {
            int gr = row0 + mf * 16 + kg * 4 + j;
            if (gr < M) {
#pragma unroll
                for (int nf = 0; nf < 4; nf++)
                    C16[(size_t)gr * 256 + (w << 6) + (nf << 4) + fr] = f2bf(acc[mf][nf][j]);
            }
        }
    float asv[4], adv[4];
#pragma unroll
    for (int nf = 0; nf < 4; nf++) {
        int col = (w << 6) + (nf << 4) + fr;
        asv[nf] = asf[col]; adv[nf] = adf[col];
    }
#pragma unroll
    for (int mf = 0; mf < 2; mf++)
#pragma unroll
        for (int j = 0; j < 4; j++) {
            float ps = acc[mf][0][j] * asv[0] + acc[mf][1][j] * asv[1] + acc[mf][2][j] * asv[2] + acc[mf][3][j] * asv[3];
            float pd = acc[mf][0][j] * adv[0] + acc[mf][1][j] * adv[1] + acc[mf][2][j] * adv[2] + acc[mf][3][j] * adv[3];
#pragma unroll
            for (int o = 1; o < 16; o <<= 1) { ps += __shfl_xor(ps, o); pd += __shfl_xor(pd, o); }
            if (fr == 0) {
                int gr = row0 + mf * 16 + kg * 4 + j;
                if (gr < M) {
                    as_out[gr * 4 + w] = ps;
                    ad_out[gr * 4 + w] = pd;
                }
            }
        }
}

// ================= compact+sort+gather from bins (atomic-free) =================
__device__ __forceinline__ void compact_dev(int bid, const int* __restrict__ offs,
                                            const int* __restrict__ bins,
                                            const int* __restrict__ spill, const int* __restrict__ spill_cnt,
                                            const int* __restrict__ ei, const float* __restrict__ ew,
                                            const float* __restrict__ sumw, int E, int N,
                                            int* __restrict__ csr_src, float* __restrict__ csr_w) {
    int lane = threadIdx.x & 63;
    int n = (bid << 2) + (threadIdx.x >> 6);
    if (n >= N) return;
    int s0 = offs[n];
    int d = offs[n + 1] - s0;
    if (d <= 0) return;
    if (d <= 64) {
        int key = (lane < d) ? bins[(size_t)n * 128 + 1 + lane] : 0x7fffffff;
        int rank = 0;
        for (int j = 0; j < d; j++) {
            int kj = __shfl(key, j);
            rank += (kj < key) ? 1 : 0;
        }
        if (lane < d) {
            int s; float wv;
            if (key < E) { s = ei[key]; wv = ew[key]; }
            else         { s = key - E; wv = *sumw / (float)E; }
            csr_src[s0 + rank] = s;
            csr_w[s0 + rank] = wv;
        }
    } else {
        if (lane == 0) {
            int m = (d < BINCAP) ? d : BINCAP;
            for (int i = 0; i < m; i++) csr_src[s0 + i] = bins[(size_t)n * 128 + 1 + i];
            int cnt = m;
            int st = *spill_cnt;
            for (int k = 0; k < st; k++)
                if (spill[2 * k] == n) csr_src[s0 + cnt++] = spill[2 * k + 1];
            for (int i = s0 + 1; i < s0 + d; i++) {
                int ke = csr_src[i];
                int j = i - 1;
                while (j >= s0 && csr_src[j] > ke) { csr_src[j + 1] = csr_src[j]; j--; }
                csr_src[j + 1] = ke;
            }
        }
        __threadfence();
        __builtin_amdgcn_wave_barrier();
        for (int i = lane; i < d; i += 64) {
            int e = csr_src[s0 + i];
            int s; float wv;
            if (e < E) { s = ei[e]; wv = ew[e]; }
            else       { s = e - E; wv = *sumw / (float)E; }
            csr_src[s0 + i] = s;
            csr_w[s0 + i] = wv;
        }
    }
}

// ================= merged: gemm layer-1 + compact/sort/gather =================
__global__ __launch_bounds__(256) void k_gemm_sort(int MB,
    const unsigned short* __restrict__ A16, const unsigned short* __restrict__ Bt16, int M,
    const float* __restrict__ asf, const float* __restrict__ adf,
    unsigned short* __restrict__ C16, float* __restrict__ as_out, float* __restrict__ ad_out,
    const int* __restrict__ offs, const int* __restrict__ bins,
    const int* __restrict__ spill, const int* __restrict__ spill_cnt,
    const int* __restrict__ ei, const float* __restrict__ ew,
    const float* __restrict__ sumw, int E,
    int* __restrict__ csr_src, float* __restrict__ csr_w) {
    if ((int)blockIdx.x < MB)
        gemm_dev(blockIdx.x, A16, Bt16, M, asf, adf, C16, as_out, ad_out);
    else
        compact_dev(blockIdx.x - MB, offs, bins, spill, spill_cnt, ei, ew, sumw, E, M, csr_src, csr_w);
}

// ================= standalone gemm (layer 2) =================
__global__ __launch_bounds__(256) void gemm_mfma(
    const unsigned short* __restrict__ A16, const unsigned short* __restrict__ Bt16, int M,
    const float* __restrict__ asf, const float* __restrict__ adf,
    unsigned short* __restrict__ C16, float* __restrict__ as_out, float* __restrict__ ad_out) {
    gemm_dev(blockIdx.x, A16, Bt16, M, asf, adf, C16, as_out, ad_out);
}

// ================= fused GAT + bias + LN + ELU -> bf16 out =================
// No online max-shift: softmax is shift-invariant and |logits| << 80 (fminf clamp as insurance).
// Vector accumulators (f32x4) -> v_pk_fma_f32 on the gather FMAs.
#define ACC8V(u, q) do { \
    f32x4 va = { bf2f_lo((u).x), bf2f_hi((u).x), bf2f_lo((u).y), bf2f_hi((u).y) }; \
    f32x4 vb = { bf2f_lo((u).z), bf2f_hi((u).z), bf2f_lo((u).w), bf2f_hi((u).w) }; \
    accA += va * (q); accB += vb * (q); } while (0)

__global__ __launch_bounds__(256) void gat_kernel(
    const unsigned short* __restrict__ xp16, const int* __restrict__ offs,
    const int* __restrict__ csr_src, const float* __restrict__ csr_w,
    const float* __restrict__ as_, const float* __restrict__ ad_,
    const float* __restrict__ cvec, const float* __restrict__ bias,
    const float* __restrict__ ln_g, const float* __restrict__ ln_b,
    int N, unsigned short* __restrict__ out16) {
    __shared__ float p_lds[4][256];
    __shared__ int   s_lds[4][64];
    int lane = threadIdx.x & 63;
    int wid = threadIdx.x >> 6;
    int n = (blockIdx.x << 2) + wid;
    if (n >= N) return;
    int start = offs[n], end = offs[n + 1];
    int e0 = lane >> 5;
    int colb = lane & 31;
    int hq2 = colb >> 3;
    const unsigned short* xbase = xp16 + (size_t)colb * 8;
    float4 adv = *(const float4*)(ad_ + (size_t)n * 4);
    float c0 = cvec[0], c1 = cvec[1], c2 = cvec[2], c3 = cvec[3];
    float dn = 0.f;
    f32x4 accA = (f32x4){0.f, 0.f, 0.f, 0.f};
    f32x4 accB = (f32x4){0.f, 0.f, 0.f, 0.f};

    for (int base = start; base < end; base += 64) {
        int idx = base + lane;
        bool act = idx < end;
        int s = act ? csr_src[idx] : 0;
        float w = act ? csr_w[idx] : 0.f;
        float4 av = *(const float4*)(as_ + (size_t)s * 4);
        float l0 = av.x + adv.x + w * c0; l0 = l0 >= 0.f ? l0 : NEG_SLOPE * l0;
        float l1 = av.y + adv.y + w * c1; l1 = l1 >= 0.f ? l1 : NEG_SLOPE * l1;
        float l2 = av.z + adv.z + w * c2; l2 = l2 >= 0.f ? l2 : NEG_SLOPE * l2;
        float l3 = av.w + adv.w + w * c3; l3 = l3 >= 0.f ? l3 : NEG_SLOPE * l3;
        float p0 = act ? __expf(fminf(l0, 80.f)) : 0.f;
        float p1 = act ? __expf(fminf(l1, 80.f)) : 0.f;
        float p2 = act ? __expf(fminf(l2, 80.f)) : 0.f;
        float p3 = act ? __expf(fminf(l3, 80.f)) : 0.f;
        float4 pv = { p0, p1, p2, p3 };
        *(float4*)&p_lds[wid][lane << 2] = pv;
        s_lds[wid][lane] = s;
        int cnt = end - base; if (cnt > 64) cnt = 64;
        int k = 0;
        for (; k + 8 <= cnt; k += 8) {
            int i0 = k + e0, i1 = k + 2 + e0, i2 = k + 4 + e0, i3 = k + 6 + e0;
            int s0 = s_lds[wid][i0], s1 = s_lds[wid][i1], s2 = s_lds[wid][i2], s3 = s_lds[wid][i3];
            uint4 u0 = *(const uint4*)(xbase + (size_t)s0 * 256);
            uint4 u1 = *(const uint4*)(xbase + (size_t)s1 * 256);
            uint4 u2 = *(const uint4*)(xbase + (size_t)s2 * 256);
            uint4 u3 = *(const uint4*)(xbase + (size_t)s3 * 256);
            float q0 = p_lds[wid][(i0 << 2) + hq2];
            float q1 = p_lds[wid][(i1 << 2) + hq2];
            float q2 = p_lds[wid][(i2 << 2) + hq2];
            float q3 = p_lds[wid][(i3 << 2) + hq2];
            dn += q0 + q1 + q2 + q3;
            ACC8V(u0, q0); ACC8V(u1, q1); ACC8V(u2, q2); ACC8V(u3, q3);
        }
        for (; k < cnt; k += 2) {
            int i = k + e0;
            bool v = i < cnt;
            int si = s_lds[wid][v ? i : 0];
            float qi = v ? p_lds[wid][(i << 2) + hq2] : 0.f;
            uint4 u = *(const uint4*)(xbase + (size_t)si * 256);
            dn += qi;
            ACC8V(u, qi);
        }
    }
#pragma unroll
    for (int o = 32; o == 32; o = 0) {
        accA[0] += __shfl_xor(accA[0], 32); accA[1] += __shfl_xor(accA[1], 32);
        accA[2] += __shfl_xor(accA[2], 32); accA[3] += __shfl_xor(accA[3], 32);
        accB[0] += __shfl_xor(accB[0], 32); accB[1] += __shfl_xor(accB[1], 32);
        accB[2] += __shfl_xor(accB[2], 32); accB[3] += __shfl_xor(accB[3], 32);
        dn += __shfl_xor(dn, 32);
    }
    float inv = 1.f / dn;
    int cb8 = colb << 3;
    float4 bA = *(const float4*)(bias + cb8);
    float4 bB = *(const float4*)(bias + cb8 + 4);
    float o0 = accA[0] * inv + bA.x, o1 = accA[1] * inv + bA.y, o2 = accA[2] * inv + bA.z, o3 = accA[3] * inv + bA.w;
    float o4 = accB[0] * inv + bB.x, o5 = accB[1] * inv + bB.y, o6 = accB[2] * inv + bB.z, o7 = accB[3] * inv + bB.w;
    float part = ((o0 + o1) + (o2 + o3)) + ((o4 + o5) + (o6 + o7));
    for (int o = 16; o; o >>= 1) part += __shfl_xor(part, o);
    float mu = part * (1.f / 256.f);
    float d0 = o0 - mu, d1 = o1 - mu, d2 = o2 - mu, d3 = o3 - mu;
    float d4 = o4 - mu, d5 = o5 - mu, d6 = o6 - mu, d7 = o7 - mu;
    float vpart = ((d0 * d0 + d1 * d1) + (d2 * d2 + d3 * d3)) + ((d4 * d4 + d5 * d5) + (d6 * d6 + d7 * d7));
    for (int o = 16; o; o >>= 1) vpart += __shfl_xor(vpart, o);
    float rstd = rsqrtf(vpart * (1.f / 256.f) + LN_EPS);
    float4 gA = *(const float4*)(ln_g + cb8), gB = *(const float4*)(ln_g + cb8 + 4);
    float4 eA = *(const float4*)(ln_b + cb8), eB = *(const float4*)(ln_b + cb8 + 4);
    float y0 = d0 * rstd * gA.x + eA.x; y0 = y0 > 0.f ? y0 : __expf(y0) - 1.f;
    float y1 = d1 * rstd * gA.y + eA.y; y1 = y1 > 0.f ? y1 : __expf(y1) - 1.f;
    float y2 = d2 * rstd * gA.z + eA.z; y2 = y2 > 0.f ? y2 : __expf(y2) - 1.f;
    float y3 = d3 * rstd * gA.w + eA.w; y3 = y3 > 0.f ? y3 : __expf(y3) - 1.f;
    float y4 = d4 * rstd * gB.x + eB.x; y4 = y4 > 0.f ? y4 : __expf(y4) - 1.f;
    float y5 = d5 * rstd * gB.y + eB.y; y5 = y5 > 0.f ? y5 : __expf(y5) - 1.f;
    float y6 = d6 * rstd * gB.z + eB.z; y6 = y6 > 0.f ? y6 : __expf(y6) - 1.f;
    float y7 = d7 * rstd * gB.w + eB.w; y7 = y7 > 0.f ? y7 : __expf(y7) - 1.f;
    if (lane < 32) {
        uint4 ov;
        ov.x = ((unsigned int)f2bf(y1) << 16) | f2bf(y0);
        ov.y = ((unsigned int)f2bf(y3) << 16) | f2bf(y2);
        ov.z = ((unsigned int)f2bf(y5) << 16) | f2bf(y4);
        ov.w = ((unsigned int)f2bf(y7) << 16) | f2bf(y6);
        *(uint4*)(out16 + (size_t)n * HID + cb8) = ov;
    }
}

// ================= batch mean pool (bf16 input), 4-way unrolled =================
__device__ __forceinline__ int lower_bound_i(const int* a, int n, int key) {
    int lo = 0, hi = n;
    while (lo < hi) { int mid = (lo + hi) >> 1; if (a[mid] < key) lo = mid + 1; else hi = mid; }
    return lo;
}

__global__ __launch_bounds__(256) void pool_kernel(const unsigned short* __restrict__ h, const int* __restrict__ batch,
                                                   int N, float* __restrict__ out) {
    int b = blockIdx.x;
    int lo = lower_bound_i(batch, N, b);
    int hi = lower_bound_i(batch, N, b + 1);
    float a0 = 0.f, a1 = 0.f, a2 = 0.f, a3 = 0.f;
    int n = lo;
    for (; n + 4 <= hi; n += 4) {
        a0 += bf2f_u(h[(size_t)(n + 0) * HID + threadIdx.x]);
        a1 += bf2f_u(h[(size_t)(n + 1) * HID + threadIdx.x]);
        a2 += bf2f_u(h[(size_t)(n + 2) * HID + threadIdx.x]);
        a3 += bf2f_u(h[(size_t)(n + 3) * HID + threadIdx.x]);
    }
    for (; n < hi; n++) a0 += bf2f_u(h[(size_t)n * HID + threadIdx.x]);
    float acc = (a0 + a1) + (a2 + a3);
    out[(size_t)b * HID + threadIdx.x] = acc / fmaxf((float)(hi - lo), 1.f);
}

extern "C" void kernel_launch(void* const* d_in, const int* in_sizes, int n_in,
                              void* d_out, int out_size, void* d_ws, size_t ws_size,
                              hipStream_t stream) {
    const float* x    = (const float*)d_in[0];
    const int*   ei   = (const int*)d_in[1];
    const float* ew   = (const float*)d_in[2];
    const int*   batch= (const int*)d_in[3];
    const float* W1   = (const float*)d_in[4];
    const float* as1  = (const float*)d_in[5];
    const float* ad1  = (const float*)d_in[6];
    const float* ae1  = (const float*)d_in[7];
    const float* We1  = (const float*)d_in[8];
    const float* b1   = (const float*)d_in[9];
    const float* W2   = (const float*)d_in[10];
    const float* as2  = (const float*)d_in[11];
    const float* ad2  = (const float*)d_in[12];
    const float* ae2  = (const float*)d_in[13];
    const float* We2  = (const float*)d_in[14];
    const float* b2   = (const float*)d_in[15];
    const float* ln1g = (const float*)d_in[16];
    const float* ln1b = (const float*)d_in[17];
    const float* ln2g = (const float*)d_in[18];
    const float* ln2b = (const float*)d_in[19];

    int N = in_sizes[3];
    int E = in_sizes[2];
    int FIN = in_sizes[0] / N;
    int EN = E + N;
    int B = out_size / HID;
    float* outp = (float*)d_out;
    int NB = (N + 255) / 256;
    int NH = (EN + 1023) / 1024;

    char* ws = (char*)d_ws;
    size_t off = 0;
    auto alloc = [&](size_t bytes) { void* p = ws + off; off = (off + bytes + 255) & ~(size_t)255; return p; };
    float* sumw      = (float*)alloc(4);                      // zeroed
    int*   spill_cnt = (int*)  alloc(4);                      // zeroed
    int*   bins      = (int*)  alloc((size_t)N * 128 * 4);    // zeroed (row counters at [n*128])
    size_t zero_bytes = 512 + (size_t)N * 128 * 4;
    float* partials= (float*)alloc(256 * 4);
    int*   bsum    = (int*)  alloc(256 * 4);
    int*   deg     = (int*)  alloc((size_t)N * 4);
    int*   offs    = (int*)  alloc((size_t)(N + 1) * 4);
    int*   spill   = (int*)  alloc((size_t)EN * 2 * 4);
    int*   csr_src = (int*)  alloc((size_t)EN * 4);
    float* csr_w   = (float*)alloc((size_t)EN * 4);
    float* asb     = (float*)alloc((size_t)N * 4 * 4);
    float* adb     = (float*)alloc((size_t)N * 4 * 4);
    float* cc      = (float*)alloc(64);
    unsigned short* w1_16 = (unsigned short*)alloc((size_t)HID * HID * 2);
    unsigned short* w2_16 = (unsigned short*)alloc((size_t)HID * HID * 2);
    unsigned short* x16   = (unsigned short*)alloc((size_t)N * HID * 2);  // x -> h1 -> h2 (reused)
    unsigned short* xp16  = (unsigned short*)alloc((size_t)N * HID * 2);
    (void)ws_size; (void)n_in;

    int MB = (N + 31) / 32;
    int NC = (N + 3) / 4;

    (void)hipMemsetAsync(d_ws, 0, zero_bytes, stream);
    k_pre<<<NH + 256 + 512 + N, 256, 0, stream>>>(ew, E, ei, N, EN, NH, partials,
                                                  bins, spill, spill_cnt,
                                                  W1, W2, w1_16, w2_16, FIN, x, x16, FIN);
    k_scanred_coeff<<<NB + 2, 256, 0, stream>>>(bins, N, NB, deg, bsum, partials, sumw, We1, ae1, We2, ae2, cc, cc + 4);
    k_scan_apply<<<NB, 256, 0, stream>>>(deg, N, NB, bsum, offs);
    // layer-1 gemm || atomic-free compact+sort+gather
    k_gemm_sort<<<MB + NC, 256, 0, stream>>>(MB, x16, w1_16, N, as1, ad1, xp16, asb, adb,
                                             offs, bins, spill, spill_cnt, ei, ew, sumw, E, csr_src, csr_w);
    // layer 1 gat
    gat_kernel<<<NC, 256, 0, stream>>>(xp16, offs, csr_src, csr_w, asb, adb, cc, b1, ln1g, ln1b, N, x16);
    // layer 2
    gemm_mfma<<<MB, 256, 0, stream>>>(x16, w2_16, N, as2, ad2, xp16, asb, adb);
    gat_kernel<<<NC, 256, 0, stream>>>(xp16, offs, csr_src, csr_w, asb, adb, cc + 4, b2, ln2g, ln2b, N, x16);
    // pool
    pool_kernel<<<B, 256, 0, stream>>>(x16, batch, N, outp);
}